// Round 10
// baseline (265.408 us; speedup 1.0000x reference)
//
#include <hip/hip_runtime.h>

// ---------------------------------------------------------------------------
// SE3 conv layer, 6-dispatch pipeline:
//   memset -> prep (bfrag f16 pack + W1T pack + dst histogram) -> scan
//   -> scatter (CSR pos + sh->f16 copy) -> edge (f16 MFMA, barrier-free)
//   -> gather (linear segmented reduction + self-interaction)
// mix rows: 96 B f16 (16 u32 of (l0,l1) pairs + 16 f16 l2), CSR-ordered.
// ws: [ mix E*48 f16 | offs N+1 | curs N | pos E | shs E*10 f16 | bfrag | W1T ]
// ---------------------------------------------------------------------------

typedef _Float16 f16x2 __attribute__((ext_vector_type(2)));
typedef _Float16 f16x8 __attribute__((ext_vector_type(8)));
typedef __fp16  g16x2 __attribute__((ext_vector_type(2)));   // cvt_pkrtz result type
typedef float f32x4 __attribute__((ext_vector_type(4)));

union AFrag { unsigned int u[4]; f16x2 h2[4]; f16x8 v; };
union BFrag { uint4 u4; f16x8 v; };
union HW { g16x2 g; f16x2 f; unsigned int u; };

// ------------- prep: bfrag pack + W1T pack + dst histogram ------------------
// Bfrag[f][lane][j], f = ks*3+nt, ku = ks*32 + (lane>>4)*8 + j,
// k=ku>>4, u=ku&15, n = nt*16 + (lane&15), l=n>>4, v=n&15; val = W2/32.
// W1T[k][u] = W1[u][k] * 0.25.

__global__ __launch_bounds__(256)
void prep_kernel(const float* __restrict__ W2, const float* __restrict__ W1,
                 _Float16* __restrict__ bfrag, float* __restrict__ w1t,
                 const int* __restrict__ ei, int* __restrict__ counts, int E) {
    int t = blockIdx.x * 256 + threadIdx.x;
    if (t < E) atomicAdd(&counts[ei[E + t] + 1], 1);
    if (t < 96 * 512) {
        int f = t >> 9;
        int rr = t & 511;
        int lane = rr >> 3, j = rr & 7;
        int ks = f / 3, nt = f - 3 * ks;
        int q = lane >> 4, c = lane & 15;
        int ku = ks * 32 + q * 8 + j;
        int k = ku >> 4, u = ku & 15;
        int n = nt * 16 + c;
        int l = n >> 4, v = n & 15;
        float val = W2[(size_t)k * 768 + l * 256 + u * 16 + v] * 0.03125f;
        bfrag[t] = (_Float16)val;
    }
    if (t < 1024) {
        int k = t >> 4, u = t & 15;
        w1t[t] = W1[u * 64 + k] * 0.25f;
    }
}

// chunk-serial scan: 1 block, each thread owns ceil(n/1024) contiguous elems.
__global__ __launch_bounds__(1024)
void scan_kernel(int* __restrict__ data, int n) {
    __shared__ int wsum[16];
    int tid = threadIdx.x, lane = tid & 63, wid = tid >> 6;
    int ch = (n + 1023) >> 10;
    int beg = tid * ch;
    int end = beg + ch; if (end > n) end = n;

    int s = 0;
    for (int i = beg; i < end; ++i) s += data[i];

    int v = s;
    #pragma unroll
    for (int off = 1; off < 64; off <<= 1) {
        int t = __shfl_up(v, off, 64);
        if (lane >= off) v += t;
    }
    if (lane == 63) wsum[wid] = v;
    __syncthreads();
    if (wid == 0 && lane < 16) {
        int w = wsum[lane];
        #pragma unroll
        for (int off = 1; off < 16; off <<= 1) {
            int t = __shfl_up(w, off, 16);
            if (lane >= off) w += t;
        }
        wsum[lane] = w;
    }
    __syncthreads();
    int run = (v - s) + (wid > 0 ? wsum[wid - 1] : 0);   // exclusive offset
    for (int i = beg; i < end; ++i) {
        run += data[i];
        data[i] = run;
    }
}

// scatter: claim CSR slot, record pos[e], copy sh row to CSR order as f16.
__global__ __launch_bounds__(256)
void scatter_kernel(const int* __restrict__ ei, const float* __restrict__ sh,
                    const int* __restrict__ offs, int* __restrict__ cursor,
                    int* __restrict__ pos, _Float16* __restrict__ shs, int E) {
    int e = blockIdx.x * blockDim.x + threadIdx.x;
    if (e >= E) return;
    int dst = ei[E + e];
    int p = offs[dst] + atomicAdd(&cursor[dst], 1);
    pos[e] = p;
    const float* s = sh + (size_t)e * 9;
    _Float16* d = shs + (size_t)p * 10;
    #pragma unroll
    for (int j = 0; j < 9; ++j) d[j] = (_Float16)s[j];
}

// --------------------------- MFMA edge kernel ------------------------------
// block = 256 = 4 waves; wave owns 64 edges (4 M-tiles of 16). Barrier-free.

__global__ __launch_bounds__(256, 5)
void edge_mfma_kernel(const float* __restrict__ nf, const int* __restrict__ ei,
                      const float* __restrict__ radial, const float* __restrict__ w1t,
                      const _Float16* __restrict__ bfrag, const int* __restrict__ pos,
                      _Float16* __restrict__ mixs, int E) {
    __shared__ unsigned int h_lds[4][64][32];   // f16 pairs (k=2t,2t+1), XOR-swizzled

    int tid = threadIdx.x;
    int wave = tid >> 6;
    int lane = tid & 63;
    int r_ = lane & 15;
    int q  = lane >> 4;
    int qh = q >> 1;                 // which half of the h-pair this lane needs
    int ul = (q & 1) * 8;            // u base for A-frag
    unsigned int sel = qh ? 0x03020302u : 0x01000100u;   // v_perm dup selector

    int ebase = blockIdx.x * 256 + wave * 64;

    // ---- phase 0: x rows for the wave's 4 M-tiles (issue early), f16 pack ----
    HW xp[4][4];
    #pragma unroll
    for (int m = 0; m < 4; ++m) {
        int e = ebase + m * 16 + r_; if (e >= E) e = E - 1;
        int src = ei[e];
        const float* xpp = nf + (size_t)src * 16 + ul;
        float4 a = *(const float4*)xpp;
        float4 b = *(const float4*)(xpp + 4);
        xp[m][0].g = __builtin_amdgcn_cvt_pkrtz(a.x, a.y);
        xp[m][1].g = __builtin_amdgcn_cvt_pkrtz(a.z, a.w);
        xp[m][2].g = __builtin_amdgcn_cvt_pkrtz(b.x, b.y);
        xp[m][3].g = __builtin_amdgcn_cvt_pkrtz(b.z, b.w);
    }

    // ---- phase 1: lane = edge; W1T read via scalar cache (wave-uniform) ----
    {
        int e = ebase + lane; if (e >= E) e = E - 1;
        const float* rp = radial + (size_t)e * 16;
        float4 r0 = *(const float4*)(rp);
        float4 r1 = *(const float4*)(rp + 4);
        float4 r2 = *(const float4*)(rp + 8);
        float4 r3 = *(const float4*)(rp + 12);
        int swz = lane & 31;
        float hprev = 0.0f;
        #pragma unroll 8
        for (int k = 0; k < 64; ++k) {
            const float4* wr = (const float4*)(w1t + (k << 4));   // uniform -> s_load
            float4 w0 = wr[0], w1v = wr[1], w2v = wr[2], w3v = wr[3];
            float z = r0.x * w0.x;
            z = fmaf(r0.y, w0.y, z);  z = fmaf(r0.z, w0.z, z);  z = fmaf(r0.w, w0.w, z);
            z = fmaf(r1.x, w1v.x, z); z = fmaf(r1.y, w1v.y, z); z = fmaf(r1.z, w1v.z, z); z = fmaf(r1.w, w1v.w, z);
            z = fmaf(r2.x, w2v.x, z); z = fmaf(r2.y, w2v.y, z); z = fmaf(r2.z, w2v.z, z); z = fmaf(r2.w, w2v.w, z);
            z = fmaf(r3.x, w3v.x, z); z = fmaf(r3.y, w3v.y, z); z = fmaf(r3.z, w3v.z, z); z = fmaf(r3.w, w3v.w, z);
            float h = z * __builtin_amdgcn_rcpf(1.0f + __expf(-z));   // silu
            if (k & 1) {
                HW w; w.g = __builtin_amdgcn_cvt_pkrtz(hprev, h);     // (k-1, k)
                h_lds[wave][lane][(k >> 1) ^ swz] = w.u;
            } else {
                hprev = h;
            }
        }
    }
    // h_lds is per-wave private; within-wave program order suffices (no barrier)

    // ---- phase 2: K-loop, 32 steps of K=32 ----
    f32x4 acc[4][3];
    #pragma unroll
    for (int m = 0; m < 4; ++m)
        #pragma unroll
        for (int nt = 0; nt < 3; ++nt)
            acc[m][nt] = (f32x4){0.f, 0.f, 0.f, 0.f};

    #pragma unroll 4
    for (int ks = 0; ks < 32; ++ks) {
        BFrag b[3];
        #pragma unroll
        for (int nt = 0; nt < 3; ++nt)
            b[nt].u4 = *(const uint4*)(bfrag + (size_t)(ks * 3 + nt) * 512 + lane * 8);
        #pragma unroll
        for (int m = 0; m < 4; ++m) {
            int el = m * 16 + r_;
            unsigned int hw = h_lds[wave][el][ks ^ (el & 31)];
            HW hv; hv.u = __builtin_amdgcn_perm(hw, hw, sel);  // dup needed half
            AFrag a;
            #pragma unroll
            for (int p2 = 0; p2 < 4; ++p2)
                a.h2[p2] = hv.f * xp[m][p2].f;                 // v_pk_mul_f16
            #pragma unroll
            for (int nt = 0; nt < 3; ++nt)
                acc[m][nt] = __builtin_amdgcn_mfma_f32_16x16x32_f16(a.v, b[nt].v, acc[m][nt], 0, 0, 0);
        }
    }

    // ---- epilogue: C layout col=r_, row=q*4+i; write 96-B f16 rows at pos ----
    unsigned int* mixu = (unsigned int*)mixs;
    #pragma unroll
    for (int m = 0; m < 4; ++m) {
        #pragma unroll
        for (int i = 0; i < 4; ++i) {
            int e = ebase + m * 16 + q * 4 + i;
            if (e < E) {
                int p = pos[e];
                HW pr; pr.g = __builtin_amdgcn_cvt_pkrtz(acc[m][0][i], acc[m][1][i]);
                mixu[(size_t)p * 24 + r_] = pr.u;
                mixs[(size_t)p * 48 + 32 + r_] = (_Float16)acc[m][2][i];
            }
        }
    }
}

// ------------------------------ gather -------------------------------------
// mix (96-B f16 rows) and sh (20-B f16 rows) in CSR order -> linear reads.

__global__ __launch_bounds__(256)
void gather_kernel(const _Float16* __restrict__ mixs, const _Float16* __restrict__ shs,
                   const int* __restrict__ offs,
                   const float* __restrict__ nf, const float* __restrict__ Wsi,
                   float* __restrict__ out, int N) {
    int node = blockIdx.x * 4 + (threadIdx.x >> 6);
    if (node >= N) return;
    int lane = threadIdx.x & 63;

    // channel c -> (f16 half-index within 48-half mix row, sh index)
    auto chmap = [](int c, int& hi, int& si) {
        if (c < 16)      { hi = 2 * c;           si = 0; }
        else if (c < 64) { int t = c - 16; hi = 2 * (t / 3) + 1; si = 1 + t % 3; }
        else             { int t = c - 64; hi = 32 + t / 5;      si = 4 + t % 5; }
    };
    int hi0, si0, hi1, si1, hi2 = 0, si2 = 0;
    chmap(lane, hi0, si0);
    chmap(lane + 64, hi1, si1);
    if (lane < 16) chmap(lane + 128, hi2, si2);

    float a0 = 0.f, a1 = 0.f, a2 = 0.f;
    float b0 = 0.f, b1 = 0.f, b2 = 0.f;
    float c0 = 0.f, c1 = 0.f, c2 = 0.f;
    float d0 = 0.f, d1 = 0.f, d2 = 0.f;
    int off = offs[node], end = offs[node + 1];
    int i = off;
    for (; i + 3 < end; i += 4) {
        const _Float16* m0 = mixs + (size_t)i * 48;
        const _Float16* m1 = m0 + 48;
        const _Float16* m2 = m0 + 96;
        const _Float16* m3 = m0 + 144;
        const _Float16* s0 = shs + (size_t)i * 10;
        const _Float16* s1 = s0 + 10;
        const _Float16* s2 = s0 + 20;
        const _Float16* s3 = s0 + 30;
        a0 = fmaf((float)m0[hi0], (float)s0[si0], a0);
        b0 = fmaf((float)m1[hi0], (float)s1[si0], b0);
        c0 = fmaf((float)m2[hi0], (float)s2[si0], c0);
        d0 = fmaf((float)m3[hi0], (float)s3[si0], d0);
        a1 = fmaf((float)m0[hi1], (float)s0[si1], a1);
        b1 = fmaf((float)m1[hi1], (float)s1[si1], b1);
        c1 = fmaf((float)m2[hi1], (float)s2[si1], c1);
        d1 = fmaf((float)m3[hi1], (float)s3[si1], d1);
        if (lane < 16) {
            a2 = fmaf((float)m0[hi2], (float)s0[si2], a2);
            b2 = fmaf((float)m1[hi2], (float)s1[si2], b2);
            c2 = fmaf((float)m2[hi2], (float)s2[si2], c2);
            d2 = fmaf((float)m3[hi2], (float)s3[si2], d2);
        }
    }
    for (; i < end; ++i) {
        const _Float16* m0 = mixs + (size_t)i * 48;
        const _Float16* s0 = shs + (size_t)i * 10;
        a0 = fmaf((float)m0[hi0], (float)s0[si0], a0);
        a1 = fmaf((float)m0[hi1], (float)s0[si1], a1);
        if (lane < 16) a2 = fmaf((float)m0[hi2], (float)s0[si2], a2);
    }
    a0 += b0 + c0 + d0;
    a1 += b1 + c1 + d1;
    a2 += b2 + c2 + d2;

    if (lane < 16) {   // self-interaction, 0e->0e only
        const float* xr = nf + (size_t)node * 16;
        float si = 0.0f;
        #pragma unroll
        for (int u = 0; u < 16; ++u)
            si = fmaf(xr[u], Wsi[u * 16 + lane], si);
        a0 = fmaf(si, 0.25f, a0);
    }

    float* orow = out + (size_t)node * 144;
    orow[lane] = a0;
    orow[lane + 64] = a1;
    if (lane < 16) orow[lane + 128] = a2;
}

// ------------------------- fallback (atomic path) --------------------------

__global__ __launch_bounds__(256)
void si_init_kernel(const float* __restrict__ nf, const float* __restrict__ Wsi,
                    float* __restrict__ out, int N) {
    int t = blockIdx.x * blockDim.x + threadIdx.x;
    int total = N * 144;
    if (t >= total) return;
    int n = t / 144;
    int c = t - n * 144;
    float val = 0.0f;
    if (c < 16) {
        const float* xr = nf + n * 16;
        #pragma unroll
        for (int u = 0; u < 16; ++u)
            val = fmaf(xr[u], Wsi[u * 16 + c], val);
        val *= 0.25f;
    }
    out[t] = val;
}

__global__ __launch_bounds__(256)
void edge_kernel_atomic(const float* __restrict__ nf, const int* __restrict__ ei,
                        const float* __restrict__ sh, const float* __restrict__ radial,
                        const float* __restrict__ W1, const float* __restrict__ W2,
                        float* __restrict__ out, int E) {
    int e = blockIdx.x * blockDim.x + threadIdx.x;
    if (e >= E) return;
    int src = ei[e];
    int dst = ei[E + e];
    float r[16], x[16];
    #pragma unroll
    for (int u = 0; u < 16; ++u) r[u] = radial[e * 16 + u] * 0.25f;
    #pragma unroll
    for (int u = 0; u < 16; ++u) x[u] = nf[src * 16 + u] * 0.03125f;
    float acc[48];
    #pragma unroll
    for (int j = 0; j < 48; ++j) acc[j] = 0.0f;
    for (int k = 0; k < 64; ++k) {
        float z = 0.0f;
        #pragma unroll
        for (int u = 0; u < 16; ++u) z = fmaf(r[u], W1[u * 64 + k], z);
        float hk = z / (1.0f + __expf(-z));
        const float* w2k = W2 + k * 768;
        #pragma unroll 4
        for (int u = 0; u < 16; ++u) {
            float p = hk * x[u];
            const float* w = w2k + u * 16;
            #pragma unroll
            for (int l = 0; l < 3; ++l)
                #pragma unroll
                for (int v = 0; v < 16; ++v)
                    acc[l * 16 + v] = fmaf(p, w[l * 256 + v], acc[l * 16 + v]);
        }
    }
    const float* she = sh + e * 9;
    float* orow = out + (long)dst * 144;
    #pragma unroll
    for (int v = 0; v < 16; ++v) atomicAdd(&orow[v], acc[v] * she[0]);
    #pragma unroll
    for (int v = 0; v < 16; ++v)
        for (int m = 0; m < 3; ++m)
            atomicAdd(&orow[16 + v * 3 + m], acc[16 + v] * she[1 + m]);
    #pragma unroll
    for (int v = 0; v < 16; ++v)
        for (int m = 0; m < 5; ++m)
            atomicAdd(&orow[64 + v * 5 + m], acc[32 + v] * she[4 + m]);
}

// ---------------------------------------------------------------------------

extern "C" void kernel_launch(void* const* d_in, const int* in_sizes, int n_in,
                              void* d_out, int out_size, void* d_ws, size_t ws_size,
                              hipStream_t stream) {
    const float* nf     = (const float*)d_in[0];
    const int*   ei     = (const int*)  d_in[1];
    const float* sh     = (const float*)d_in[2];
    const float* radial = (const float*)d_in[3];
    const float* W1     = (const float*)d_in[4];
    const float* W2     = (const float*)d_in[5];
    const float* Wsi    = (const float*)d_in[6];
    float* out = (float*)d_out;

    const int N = in_sizes[0] / 16;
    const int E = in_sizes[1] / 2;

    size_t mix_bytes  = (size_t)E * 48 * sizeof(_Float16);   // 96-B f16 rows
    size_t offs_bytes = (size_t)(N + 1) * sizeof(int);
    size_t curs_bytes = (size_t)N * sizeof(int);
    size_t pos_bytes  = (size_t)E * sizeof(int);
    size_t shs_bytes  = (size_t)E * 10 * sizeof(_Float16);   // 20-B f16 sh rows
    size_t bfrag_off  = (mix_bytes + offs_bytes + curs_bytes + pos_bytes + shs_bytes + 127) & ~(size_t)127;
    size_t bfrag_bytes = 96 * 512 * sizeof(_Float16);        // 96 KB
    size_t w1t_off    = bfrag_off + bfrag_bytes;
    size_t w1t_bytes  = 1024 * sizeof(float);                // 4 KB
    size_t need = w1t_off + w1t_bytes;

    if (ws_size < need) {
        int total = N * 144;
        hipLaunchKernelGGL(si_init_kernel, dim3((total + 255) / 256), dim3(256), 0, stream,
                           nf, Wsi, out, N);
        hipLaunchKernelGGL(edge_kernel_atomic, dim3((E + 255) / 256), dim3(256), 0, stream,
                           nf, ei, sh, radial, W1, W2, out, E);
        return;
    }

    char* wsb = (char*)d_ws;
    _Float16* mixs = (_Float16*)wsb;
    int*   offs = (int*)(wsb + mix_bytes);
    int*   curs = (int*)(wsb + mix_bytes + offs_bytes);
    int*   pos  = (int*)(wsb + mix_bytes + offs_bytes + curs_bytes);
    _Float16* shs = (_Float16*)(wsb + mix_bytes + offs_bytes + curs_bytes + pos_bytes);
    _Float16* bfrag = (_Float16*)(wsb + bfrag_off);
    float* w1t = (float*)(wsb + w1t_off);

    (void)hipMemsetAsync(offs, 0, offs_bytes + curs_bytes, stream);

    int eb = (E + 255) / 256;
    hipLaunchKernelGGL(prep_kernel, dim3(eb), dim3(256), 0, stream,
                       W2, W1, bfrag, w1t, ei, offs, E);
    hipLaunchKernelGGL(scan_kernel, dim3(1), dim3(1024), 0, stream, offs, N + 1);
    hipLaunchKernelGGL(scatter_kernel, dim3(eb), dim3(256), 0, stream,
                       ei, sh, offs, curs, pos, shs, E);
    hipLaunchKernelGGL(edge_mfma_kernel, dim3(eb), dim3(256), 0, stream,
                       nf, ei, radial, w1t, bfrag, pos, mixs, E);
    hipLaunchKernelGGL(gather_kernel, dim3((N + 3) / 4), dim3(256), 0, stream,
                       mixs, shs, offs, nf, Wsi, out, N);
}

// Round 11
// 195.612 us; speedup vs baseline: 1.3568x; 1.3568x over previous
//
#include <hip/hip_runtime.h>

// ---------------------------------------------------------------------------
// SE3 conv layer, 6-dispatch pipeline:
//   memset -> prep (bfrag f16 pack + W1T pack + dst histogram) -> scan
//   -> scatter (CSR pos + sh->f16 copy) -> edge (f16 MFMA, barrier-free)
//   -> gather (linear segmented reduction + self-interaction)
// mix rows: 96 B f16 (16 u32 of (l0,l1) pairs + 16 f16 l2), CSR-ordered.
// ws: [ mix E*48 f16 | offs N+1 | curs N | pos E | shs E*10 f16 | bfrag | W1T ]
// NOTE (R10 lesson): launch_bounds(256,5) + unroll 4 -> VGPR cap + spills
// (FETCH 19->124 MB, 2.7x slower). Keep (256,4) + unroll 2.
// ---------------------------------------------------------------------------

typedef _Float16 f16x2 __attribute__((ext_vector_type(2)));
typedef _Float16 f16x8 __attribute__((ext_vector_type(8)));
typedef __fp16  g16x2 __attribute__((ext_vector_type(2)));   // cvt_pkrtz result type
typedef float f32x4 __attribute__((ext_vector_type(4)));

union AFrag { unsigned int u[4]; f16x2 h2[4]; f16x8 v; };
union BFrag { uint4 u4; f16x8 v; };
union HW { g16x2 g; f16x2 f; unsigned int u; };

// ------------- prep: bfrag pack + W1T pack + dst histogram ------------------
// Bfrag[f][lane][j], f = ks*3+nt, ku = ks*32 + (lane>>4)*8 + j,
// k=ku>>4, u=ku&15, n = nt*16 + (lane&15), l=n>>4, v=n&15; val = W2/32.
// W1T[k][u] = W1[u][k] * 0.25.

__global__ __launch_bounds__(256)
void prep_kernel(const float* __restrict__ W2, const float* __restrict__ W1,
                 _Float16* __restrict__ bfrag, float* __restrict__ w1t,
                 const int* __restrict__ ei, int* __restrict__ counts, int E) {
    int t = blockIdx.x * 256 + threadIdx.x;
    if (t < E) atomicAdd(&counts[ei[E + t] + 1], 1);
    if (t < 96 * 512) {
        int f = t >> 9;
        int rr = t & 511;
        int lane = rr >> 3, j = rr & 7;
        int ks = f / 3, nt = f - 3 * ks;
        int q = lane >> 4, c = lane & 15;
        int ku = ks * 32 + q * 8 + j;
        int k = ku >> 4, u = ku & 15;
        int n = nt * 16 + c;
        int l = n >> 4, v = n & 15;
        float val = W2[(size_t)k * 768 + l * 256 + u * 16 + v] * 0.03125f;
        bfrag[t] = (_Float16)val;
    }
    if (t < 1024) {
        int k = t >> 4, u = t & 15;
        w1t[t] = W1[u * 64 + k] * 0.25f;
    }
}

// chunk-serial scan: 1 block, each thread owns ceil(n/1024) contiguous elems.
__global__ __launch_bounds__(1024)
void scan_kernel(int* __restrict__ data, int n) {
    __shared__ int wsum[16];
    int tid = threadIdx.x, lane = tid & 63, wid = tid >> 6;
    int ch = (n + 1023) >> 10;
    int beg = tid * ch;
    int end = beg + ch; if (end > n) end = n;

    int s = 0;
    for (int i = beg; i < end; ++i) s += data[i];

    int v = s;
    #pragma unroll
    for (int off = 1; off < 64; off <<= 1) {
        int t = __shfl_up(v, off, 64);
        if (lane >= off) v += t;
    }
    if (lane == 63) wsum[wid] = v;
    __syncthreads();
    if (wid == 0 && lane < 16) {
        int w = wsum[lane];
        #pragma unroll
        for (int off = 1; off < 16; off <<= 1) {
            int t = __shfl_up(w, off, 16);
            if (lane >= off) w += t;
        }
        wsum[lane] = w;
    }
    __syncthreads();
    int run = (v - s) + (wid > 0 ? wsum[wid - 1] : 0);   // exclusive offset
    for (int i = beg; i < end; ++i) {
        run += data[i];
        data[i] = run;
    }
}

// scatter: claim CSR slot, record pos[e], copy sh row to CSR order as f16.
__global__ __launch_bounds__(256)
void scatter_kernel(const int* __restrict__ ei, const float* __restrict__ sh,
                    const int* __restrict__ offs, int* __restrict__ cursor,
                    int* __restrict__ pos, _Float16* __restrict__ shs, int E) {
    int e = blockIdx.x * blockDim.x + threadIdx.x;
    if (e >= E) return;
    int dst = ei[E + e];
    int p = offs[dst] + atomicAdd(&cursor[dst], 1);
    pos[e] = p;
    const float* s = sh + (size_t)e * 9;
    _Float16* d = shs + (size_t)p * 10;
    #pragma unroll
    for (int j = 0; j < 9; ++j) d[j] = (_Float16)s[j];
}

// --------------------------- MFMA edge kernel ------------------------------
// block = 256 = 4 waves; wave owns 64 edges (4 M-tiles of 16). Barrier-free.

__global__ __launch_bounds__(256, 4)
void edge_mfma_kernel(const float* __restrict__ nf, const int* __restrict__ ei,
                      const float* __restrict__ radial, const float* __restrict__ w1t,
                      const _Float16* __restrict__ bfrag, const int* __restrict__ pos,
                      _Float16* __restrict__ mixs, int E) {
    __shared__ unsigned int h_lds[4][64][32];   // f16 pairs (k=2t,2t+1), XOR-swizzled

    int tid = threadIdx.x;
    int wave = tid >> 6;
    int lane = tid & 63;
    int r_ = lane & 15;
    int q  = lane >> 4;
    int qh = q >> 1;                 // which half of the h-pair this lane needs
    int ul = (q & 1) * 8;            // u base for A-frag
    unsigned int sel = qh ? 0x03020302u : 0x01000100u;   // v_perm dup selector

    int ebase = blockIdx.x * 256 + wave * 64;

    // ---- phase 0: x rows for the wave's 4 M-tiles (issue early), f16 pack ----
    HW xp[4][4];
    #pragma unroll
    for (int m = 0; m < 4; ++m) {
        int e = ebase + m * 16 + r_; if (e >= E) e = E - 1;
        int src = ei[e];
        const float* xpp = nf + (size_t)src * 16 + ul;
        float4 a = *(const float4*)xpp;
        float4 b = *(const float4*)(xpp + 4);
        xp[m][0].g = __builtin_amdgcn_cvt_pkrtz(a.x, a.y);
        xp[m][1].g = __builtin_amdgcn_cvt_pkrtz(a.z, a.w);
        xp[m][2].g = __builtin_amdgcn_cvt_pkrtz(b.x, b.y);
        xp[m][3].g = __builtin_amdgcn_cvt_pkrtz(b.z, b.w);
    }

    // ---- phase 1: lane = edge; W1T read via scalar cache (wave-uniform) ----
    {
        int e = ebase + lane; if (e >= E) e = E - 1;
        const float* rp = radial + (size_t)e * 16;
        float4 r0 = *(const float4*)(rp);
        float4 r1 = *(const float4*)(rp + 4);
        float4 r2 = *(const float4*)(rp + 8);
        float4 r3 = *(const float4*)(rp + 12);
        int swz = lane & 31;
        float hprev = 0.0f;
        #pragma unroll 8
        for (int k = 0; k < 64; ++k) {
            const float4* wr = (const float4*)(w1t + (k << 4));   // uniform -> s_load
            float4 w0 = wr[0], w1v = wr[1], w2v = wr[2], w3v = wr[3];
            float z = r0.x * w0.x;
            z = fmaf(r0.y, w0.y, z);  z = fmaf(r0.z, w0.z, z);  z = fmaf(r0.w, w0.w, z);
            z = fmaf(r1.x, w1v.x, z); z = fmaf(r1.y, w1v.y, z); z = fmaf(r1.z, w1v.z, z); z = fmaf(r1.w, w1v.w, z);
            z = fmaf(r2.x, w2v.x, z); z = fmaf(r2.y, w2v.y, z); z = fmaf(r2.z, w2v.z, z); z = fmaf(r2.w, w2v.w, z);
            z = fmaf(r3.x, w3v.x, z); z = fmaf(r3.y, w3v.y, z); z = fmaf(r3.z, w3v.z, z); z = fmaf(r3.w, w3v.w, z);
            float h = z * __builtin_amdgcn_rcpf(1.0f + __expf(-z));   // silu
            if (k & 1) {
                HW w; w.g = __builtin_amdgcn_cvt_pkrtz(hprev, h);     // (k-1, k)
                h_lds[wave][lane][(k >> 1) ^ swz] = w.u;
            } else {
                hprev = h;
            }
        }
    }
    // h_lds is per-wave private; within-wave program order suffices (no barrier)

    // ---- phase 2: K-loop, 32 steps of K=32 ----
    f32x4 acc[4][3];
    #pragma unroll
    for (int m = 0; m < 4; ++m)
        #pragma unroll
        for (int nt = 0; nt < 3; ++nt)
            acc[m][nt] = (f32x4){0.f, 0.f, 0.f, 0.f};

    #pragma unroll 2
    for (int ks = 0; ks < 32; ++ks) {
        BFrag b[3];
        #pragma unroll
        for (int nt = 0; nt < 3; ++nt)
            b[nt].u4 = *(const uint4*)(bfrag + (size_t)(ks * 3 + nt) * 512 + lane * 8);
        #pragma unroll
        for (int m = 0; m < 4; ++m) {
            int el = m * 16 + r_;
            unsigned int hw = h_lds[wave][el][ks ^ (el & 31)];
            HW hv; hv.u = __builtin_amdgcn_perm(hw, hw, sel);  // dup needed half
            AFrag a;
            #pragma unroll
            for (int p2 = 0; p2 < 4; ++p2)
                a.h2[p2] = hv.f * xp[m][p2].f;                 // v_pk_mul_f16
            #pragma unroll
            for (int nt = 0; nt < 3; ++nt)
                acc[m][nt] = __builtin_amdgcn_mfma_f32_16x16x32_f16(a.v, b[nt].v, acc[m][nt], 0, 0, 0);
        }
    }

    // ---- epilogue: C layout col=r_, row=q*4+i; write 96-B f16 rows at pos ----
    unsigned int* mixu = (unsigned int*)mixs;
    #pragma unroll
    for (int m = 0; m < 4; ++m) {
        #pragma unroll
        for (int i = 0; i < 4; ++i) {
            int e = ebase + m * 16 + q * 4 + i;
            if (e < E) {
                int p = pos[e];
                HW pr; pr.g = __builtin_amdgcn_cvt_pkrtz(acc[m][0][i], acc[m][1][i]);
                mixu[(size_t)p * 24 + r_] = pr.u;
                mixs[(size_t)p * 48 + 32 + r_] = (_Float16)acc[m][2][i];
            }
        }
    }
}

// ------------------------------ gather -------------------------------------
// mix (96-B f16 rows) and sh (20-B f16 rows) in CSR order -> linear reads.

__global__ __launch_bounds__(256)
void gather_kernel(const _Float16* __restrict__ mixs, const _Float16* __restrict__ shs,
                   const int* __restrict__ offs,
                   const float* __restrict__ nf, const float* __restrict__ Wsi,
                   float* __restrict__ out, int N) {
    int node = blockIdx.x * 4 + (threadIdx.x >> 6);
    if (node >= N) return;
    int lane = threadIdx.x & 63;

    // channel c -> (f16 half-index within 48-half mix row, sh index)
    auto chmap = [](int c, int& hi, int& si) {
        if (c < 16)      { hi = 2 * c;           si = 0; }
        else if (c < 64) { int t = c - 16; hi = 2 * (t / 3) + 1; si = 1 + t % 3; }
        else             { int t = c - 64; hi = 32 + t / 5;      si = 4 + t % 5; }
    };
    int hi0, si0, hi1, si1, hi2 = 0, si2 = 0;
    chmap(lane, hi0, si0);
    chmap(lane + 64, hi1, si1);
    if (lane < 16) chmap(lane + 128, hi2, si2);

    float a0 = 0.f, a1 = 0.f, a2 = 0.f;
    float b0 = 0.f, b1 = 0.f, b2 = 0.f;
    float c0 = 0.f, c1 = 0.f, c2 = 0.f;
    float d0 = 0.f, d1 = 0.f, d2 = 0.f;
    int off = offs[node], end = offs[node + 1];
    int i = off;
    for (; i + 3 < end; i += 4) {
        const _Float16* m0 = mixs + (size_t)i * 48;
        const _Float16* m1 = m0 + 48;
        const _Float16* m2 = m0 + 96;
        const _Float16* m3 = m0 + 144;
        const _Float16* s0 = shs + (size_t)i * 10;
        const _Float16* s1 = s0 + 10;
        const _Float16* s2 = s0 + 20;
        const _Float16* s3 = s0 + 30;
        a0 = fmaf((float)m0[hi0], (float)s0[si0], a0);
        b0 = fmaf((float)m1[hi0], (float)s1[si0], b0);
        c0 = fmaf((float)m2[hi0], (float)s2[si0], c0);
        d0 = fmaf((float)m3[hi0], (float)s3[si0], d0);
        a1 = fmaf((float)m0[hi1], (float)s0[si1], a1);
        b1 = fmaf((float)m1[hi1], (float)s1[si1], b1);
        c1 = fmaf((float)m2[hi1], (float)s2[si1], c1);
        d1 = fmaf((float)m3[hi1], (float)s3[si1], d1);
        if (lane < 16) {
            a2 = fmaf((float)m0[hi2], (float)s0[si2], a2);
            b2 = fmaf((float)m1[hi2], (float)s1[si2], b2);
            c2 = fmaf((float)m2[hi2], (float)s2[si2], c2);
            d2 = fmaf((float)m3[hi2], (float)s3[si2], d2);
        }
    }
    for (; i < end; ++i) {
        const _Float16* m0 = mixs + (size_t)i * 48;
        const _Float16* s0 = shs + (size_t)i * 10;
        a0 = fmaf((float)m0[hi0], (float)s0[si0], a0);
        a1 = fmaf((float)m0[hi1], (float)s0[si1], a1);
        if (lane < 16) a2 = fmaf((float)m0[hi2], (float)s0[si2], a2);
    }
    a0 += b0 + c0 + d0;
    a1 += b1 + c1 + d1;
    a2 += b2 + c2 + d2;

    if (lane < 16) {   // self-interaction, 0e->0e only
        const float* xr = nf + (size_t)node * 16;
        float si = 0.0f;
        #pragma unroll
        for (int u = 0; u < 16; ++u)
            si = fmaf(xr[u], Wsi[u * 16 + lane], si);
        a0 = fmaf(si, 0.25f, a0);
    }

    float* orow = out + (size_t)node * 144;
    orow[lane] = a0;
    orow[lane + 64] = a1;
    if (lane < 16) orow[lane + 128] = a2;
}

// ------------------------- fallback (atomic path) --------------------------

__global__ __launch_bounds__(256)
void si_init_kernel(const float* __restrict__ nf, const float* __restrict__ Wsi,
                    float* __restrict__ out, int N) {
    int t = blockIdx.x * blockDim.x + threadIdx.x;
    int total = N * 144;
    if (t >= total) return;
    int n = t / 144;
    int c = t - n * 144;
    float val = 0.0f;
    if (c < 16) {
        const float* xr = nf + n * 16;
        #pragma unroll
        for (int u = 0; u < 16; ++u)
            val = fmaf(xr[u], Wsi[u * 16 + c], val);
        val *= 0.25f;
    }
    out[t] = val;
}

__global__ __launch_bounds__(256)
void edge_kernel_atomic(const float* __restrict__ nf, const int* __restrict__ ei,
                        const float* __restrict__ sh, const float* __restrict__ radial,
                        const float* __restrict__ W1, const float* __restrict__ W2,
                        float* __restrict__ out, int E) {
    int e = blockIdx.x * blockDim.x + threadIdx.x;
    if (e >= E) return;
    int src = ei[e];
    int dst = ei[E + e];
    float r[16], x[16];
    #pragma unroll
    for (int u = 0; u < 16; ++u) r[u] = radial[e * 16 + u] * 0.25f;
    #pragma unroll
    for (int u = 0; u < 16; ++u) x[u] = nf[src * 16 + u] * 0.03125f;
    float acc[48];
    #pragma unroll
    for (int j = 0; j < 48; ++j) acc[j] = 0.0f;
    for (int k = 0; k < 64; ++k) {
        float z = 0.0f;
        #pragma unroll
        for (int u = 0; u < 16; ++u) z = fmaf(r[u], W1[u * 64 + k], z);
        float hk = z / (1.0f + __expf(-z));
        const float* w2k = W2 + k * 768;
        #pragma unroll 4
        for (int u = 0; u < 16; ++u) {
            float p = hk * x[u];
            const float* w = w2k + u * 16;
            #pragma unroll
            for (int l = 0; l < 3; ++l)
                #pragma unroll
                for (int v = 0; v < 16; ++v)
                    acc[l * 16 + v] = fmaf(p, w[l * 256 + v], acc[l * 16 + v]);
        }
    }
    const float* she = sh + e * 9;
    float* orow = out + (long)dst * 144;
    #pragma unroll
    for (int v = 0; v < 16; ++v) atomicAdd(&orow[v], acc[v] * she[0]);
    #pragma unroll
    for (int v = 0; v < 16; ++v)
        for (int m = 0; m < 3; ++m)
            atomicAdd(&orow[16 + v * 3 + m], acc[16 + v] * she[1 + m]);
    #pragma unroll
    for (int v = 0; v < 16; ++v)
        for (int m = 0; m < 5; ++m)
            atomicAdd(&orow[64 + v * 5 + m], acc[32 + v] * she[4 + m]);
}

// ---------------------------------------------------------------------------

extern "C" void kernel_launch(void* const* d_in, const int* in_sizes, int n_in,
                              void* d_out, int out_size, void* d_ws, size_t ws_size,
                              hipStream_t stream) {
    const float* nf     = (const float*)d_in[0];
    const int*   ei     = (const int*)  d_in[1];
    const float* sh     = (const float*)d_in[2];
    const float* radial = (const float*)d_in[3];
    const float* W1     = (const float*)d_in[4];
    const float* W2     = (const float*)d_in[5];
    const float* Wsi    = (const float*)d_in[6];
    float* out = (float*)d_out;

    const int N = in_sizes[0] / 16;
    const int E = in_sizes[1] / 2;

    size_t mix_bytes  = (size_t)E * 48 * sizeof(_Float16);   // 96-B f16 rows
    size_t offs_bytes = (size_t)(N + 1) * sizeof(int);
    size_t curs_bytes = (size_t)N * sizeof(int);
    size_t pos_bytes  = (size_t)E * sizeof(int);
    size_t shs_bytes  = (size_t)E * 10 * sizeof(_Float16);   // 20-B f16 sh rows
    size_t bfrag_off  = (mix_bytes + offs_bytes + curs_bytes + pos_bytes + shs_bytes + 127) & ~(size_t)127;
    size_t bfrag_bytes = 96 * 512 * sizeof(_Float16);        // 96 KB
    size_t w1t_off    = bfrag_off + bfrag_bytes;
    size_t w1t_bytes  = 1024 * sizeof(float);                // 4 KB
    size_t need = w1t_off + w1t_bytes;

    if (ws_size < need) {
        int total = N * 144;
        hipLaunchKernelGGL(si_init_kernel, dim3((total + 255) / 256), dim3(256), 0, stream,
                           nf, Wsi, out, N);
        hipLaunchKernelGGL(edge_kernel_atomic, dim3((E + 255) / 256), dim3(256), 0, stream,
                           nf, ei, sh, radial, W1, W2, out, E);
        return;
    }

    char* wsb = (char*)d_ws;
    _Float16* mixs = (_Float16*)wsb;
    int*   offs = (int*)(wsb + mix_bytes);
    int*   curs = (int*)(wsb + mix_bytes + offs_bytes);
    int*   pos  = (int*)(wsb + mix_bytes + offs_bytes + curs_bytes);
    _Float16* shs = (_Float16*)(wsb + mix_bytes + offs_bytes + curs_bytes + pos_bytes);
    _Float16* bfrag = (_Float16*)(wsb + bfrag_off);
    float* w1t = (float*)(wsb + w1t_off);

    (void)hipMemsetAsync(offs, 0, offs_bytes + curs_bytes, stream);

    int eb = (E + 255) / 256;
    hipLaunchKernelGGL(prep_kernel, dim3(eb), dim3(256), 0, stream,
                       W2, W1, bfrag, w1t, ei, offs, E);
    hipLaunchKernelGGL(scan_kernel, dim3(1), dim3(1024), 0, stream, offs, N + 1);
    hipLaunchKernelGGL(scatter_kernel, dim3(eb), dim3(256), 0, stream,
                       ei, sh, offs, curs, pos, shs, E);
    hipLaunchKernelGGL(edge_mfma_kernel, dim3(eb), dim3(256), 0, stream,
                       nf, ei, radial, w1t, bfrag, pos, mixs, E);
    hipLaunchKernelGGL(gather_kernel, dim3((N + 3) / 4), dim3(256), 0, stream,
                       mixs, shs, offs, nf, Wsi, out, N);
}

// Round 12
// 176.561 us; speedup vs baseline: 1.5032x; 1.1079x over previous
//
#include <hip/hip_runtime.h>

// ---------------------------------------------------------------------------
// SE3 conv layer, 6-dispatch pipeline:
//   memset -> prep (bfrag f16 pack + dst histogram) -> scan
//   -> scatter (CSR pos + sh->f16 packed copy) -> edge (f16 MFMA)
//   -> gather (linear segmented reduction + self-interaction)
// mix rows: 96 B f16 (16 u32 of (l0,l1) pairs + 16 f16 l2), CSR-ordered.
// ws: [ mix E*48 f16 | offs N+1 | curs N | pos E | shs E*10 f16 | bfrag 96KB ]
// R10 lesson: launch_bounds(256,5)+unroll4 -> VGPR spills (FETCH 19->124MB).
// R11 lesson: W1T via global "uniform" loads doesn't scalarize -> +19us;
//             stage W1 in LDS (ds_read broadcast is the reliable path).
// ---------------------------------------------------------------------------

typedef _Float16 f16x2 __attribute__((ext_vector_type(2)));
typedef _Float16 f16x8 __attribute__((ext_vector_type(8)));
typedef __fp16  g16x2 __attribute__((ext_vector_type(2)));   // cvt_pkrtz result type
typedef float f32x4 __attribute__((ext_vector_type(4)));

union AFrag { unsigned int u[4]; f16x2 h2[4]; f16x8 v; };
union BFrag { uint4 u4; f16x8 v; };
union HW { g16x2 g; f16x2 f; unsigned int u; };

// ------------------- prep: bfrag pack + dst histogram -----------------------
// Bfrag[f][lane][j], f = ks*3+nt, ku = ks*32 + (lane>>4)*8 + j,
// k=ku>>4, u=ku&15, n = nt*16 + (lane&15), l=n>>4, v=n&15; val = W2/32.

__global__ __launch_bounds__(256)
void prep_kernel(const float* __restrict__ W2, _Float16* __restrict__ bfrag,
                 const int* __restrict__ ei, int* __restrict__ counts, int E) {
    int t = blockIdx.x * 256 + threadIdx.x;
    if (t < E) atomicAdd(&counts[ei[E + t] + 1], 1);
    if (t < 96 * 512) {
        int f = t >> 9;
        int rr = t & 511;
        int lane = rr >> 3, j = rr & 7;
        int ks = f / 3, nt = f - 3 * ks;
        int q = lane >> 4, c = lane & 15;
        int ku = ks * 32 + q * 8 + j;
        int k = ku >> 4, u = ku & 15;
        int n = nt * 16 + c;
        int l = n >> 4, v = n & 15;
        float val = W2[(size_t)k * 768 + l * 256 + u * 16 + v] * 0.03125f;
        bfrag[t] = (_Float16)val;
    }
}

// chunk-serial scan: 1 block, each thread owns ceil(n/1024) contiguous elems.
__global__ __launch_bounds__(1024)
void scan_kernel(int* __restrict__ data, int n) {
    __shared__ int wsum[16];
    int tid = threadIdx.x, lane = tid & 63, wid = tid >> 6;
    int ch = (n + 1023) >> 10;
    int beg = tid * ch;
    int end = beg + ch; if (end > n) end = n;

    int s = 0;
    for (int i = beg; i < end; ++i) s += data[i];

    int v = s;
    #pragma unroll
    for (int off = 1; off < 64; off <<= 1) {
        int t = __shfl_up(v, off, 64);
        if (lane >= off) v += t;
    }
    if (lane == 63) wsum[wid] = v;
    __syncthreads();
    if (wid == 0 && lane < 16) {
        int w = wsum[lane];
        #pragma unroll
        for (int off = 1; off < 16; off <<= 1) {
            int t = __shfl_up(w, off, 16);
            if (lane >= off) w += t;
        }
        wsum[lane] = w;
    }
    __syncthreads();
    int run = (v - s) + (wid > 0 ? wsum[wid - 1] : 0);   // exclusive offset
    for (int i = beg; i < end; ++i) {
        run += data[i];
        data[i] = run;
    }
}

// scatter: claim CSR slot, record pos[e], copy sh row (packed f16) to CSR order.
__global__ __launch_bounds__(256)
void scatter_kernel(const int* __restrict__ ei, const float* __restrict__ sh,
                    const int* __restrict__ offs, int* __restrict__ cursor,
                    int* __restrict__ pos, _Float16* __restrict__ shs, int E) {
    int e = blockIdx.x * blockDim.x + threadIdx.x;
    if (e >= E) return;
    int dst = ei[E + e];
    int p = offs[dst] + atomicAdd(&cursor[dst], 1);
    pos[e] = p;
    const float* s = sh + (size_t)e * 9;
    float4 s03 = *(const float4*)s;
    float4 s47 = *(const float4*)(s + 4);
    float s8 = s[8];
    unsigned int* d = (unsigned int*)(shs + (size_t)p * 10);
    HW w0, w1, w2, w3, w4;
    w0.g = __builtin_amdgcn_cvt_pkrtz(s03.x, s03.y);
    w1.g = __builtin_amdgcn_cvt_pkrtz(s03.z, s03.w);
    w2.g = __builtin_amdgcn_cvt_pkrtz(s47.x, s47.y);
    w3.g = __builtin_amdgcn_cvt_pkrtz(s47.z, s47.w);
    w4.g = __builtin_amdgcn_cvt_pkrtz(s8, 0.0f);
    d[0] = w0.u; d[1] = w1.u; d[2] = w2.u; d[3] = w3.u; d[4] = w4.u;
}

// --------------------------- MFMA edge kernel ------------------------------
// block = 256 = 4 waves; wave owns 64 edges (4 M-tiles of 16).

__global__ __launch_bounds__(256, 4)
void edge_mfma_kernel(const float* __restrict__ nf, const int* __restrict__ ei,
                      const float* __restrict__ radial, const float* __restrict__ W1,
                      const _Float16* __restrict__ bfrag, const int* __restrict__ pos,
                      _Float16* __restrict__ mixs, int E) {
    __shared__ unsigned int h_lds[4][64][32];   // f16 pairs (k=2t,2t+1), XOR-swizzled
    __shared__ float w1t[64][16];               // W1^T, pre-scaled by 1/4

    int tid = threadIdx.x;

    // stage W1^T (scaled) into LDS once per block (ds_read broadcasts later)
    for (int idx = tid; idx < 1024; idx += 256) {
        int k = idx >> 4, u = idx & 15;
        w1t[k][u] = W1[u * 64 + k] * 0.25f;
    }
    __syncthreads();

    int wave = tid >> 6;
    int lane = tid & 63;
    int r_ = lane & 15;
    int q  = lane >> 4;
    int qh = q >> 1;                 // which half of the h-pair this lane needs
    int ul = (q & 1) * 8;            // u base for A-frag
    unsigned int sel = qh ? 0x03020302u : 0x01000100u;   // v_perm dup selector

    int ebase = blockIdx.x * 256 + wave * 64;

    // ---- phase 0: x rows for the wave's 4 M-tiles (issue early), f16 pack ----
    HW xp[4][4];
    #pragma unroll
    for (int m = 0; m < 4; ++m) {
        int e = ebase + m * 16 + r_; if (e >= E) e = E - 1;
        int src = ei[e];
        const float* xpp = nf + (size_t)src * 16 + ul;
        float4 a = *(const float4*)xpp;
        float4 b = *(const float4*)(xpp + 4);
        xp[m][0].g = __builtin_amdgcn_cvt_pkrtz(a.x, a.y);
        xp[m][1].g = __builtin_amdgcn_cvt_pkrtz(a.z, a.w);
        xp[m][2].g = __builtin_amdgcn_cvt_pkrtz(b.x, b.y);
        xp[m][3].g = __builtin_amdgcn_cvt_pkrtz(b.z, b.w);
    }

    // ---- phase 1: lane = edge; k-loop with W1^T broadcast reads from LDS ----
    {
        int e = ebase + lane; if (e >= E) e = E - 1;
        const float* rp = radial + (size_t)e * 16;
        float4 r0 = *(const float4*)(rp);
        float4 r1 = *(const float4*)(rp + 4);
        float4 r2 = *(const float4*)(rp + 8);
        float4 r3 = *(const float4*)(rp + 12);
        int swz = lane & 31;
        float hprev = 0.0f;
        #pragma unroll 8
        for (int k = 0; k < 64; ++k) {
            const float4* wr = (const float4*)(&w1t[k][0]);
            float4 w0 = wr[0], w1v = wr[1], w2v = wr[2], w3v = wr[3];
            float z = r0.x * w0.x;
            z = fmaf(r0.y, w0.y, z);  z = fmaf(r0.z, w0.z, z);  z = fmaf(r0.w, w0.w, z);
            z = fmaf(r1.x, w1v.x, z); z = fmaf(r1.y, w1v.y, z); z = fmaf(r1.z, w1v.z, z); z = fmaf(r1.w, w1v.w, z);
            z = fmaf(r2.x, w2v.x, z); z = fmaf(r2.y, w2v.y, z); z = fmaf(r2.z, w2v.z, z); z = fmaf(r2.w, w2v.w, z);
            z = fmaf(r3.x, w3v.x, z); z = fmaf(r3.y, w3v.y, z); z = fmaf(r3.z, w3v.z, z); z = fmaf(r3.w, w3v.w, z);
            float h = z * __builtin_amdgcn_rcpf(1.0f + __expf(-z));   // silu
            if (k & 1) {
                HW w; w.g = __builtin_amdgcn_cvt_pkrtz(hprev, h);     // (k-1, k)
                h_lds[wave][lane][(k >> 1) ^ swz] = w.u;
            } else {
                hprev = h;
            }
        }
    }
    // h_lds is per-wave private; within-wave program order suffices (no barrier)

    // ---- phase 2: K-loop, 32 steps of K=32 ----
    f32x4 acc[4][3];
    #pragma unroll
    for (int m = 0; m < 4; ++m)
        #pragma unroll
        for (int nt = 0; nt < 3; ++nt)
            acc[m][nt] = (f32x4){0.f, 0.f, 0.f, 0.f};

    #pragma unroll 2
    for (int ks = 0; ks < 32; ++ks) {
        BFrag b[3];
        #pragma unroll
        for (int nt = 0; nt < 3; ++nt)
            b[nt].u4 = *(const uint4*)(bfrag + (size_t)(ks * 3 + nt) * 512 + lane * 8);
        #pragma unroll
        for (int m = 0; m < 4; ++m) {
            int el = m * 16 + r_;
            unsigned int hw = h_lds[wave][el][ks ^ (el & 31)];
            HW hv; hv.u = __builtin_amdgcn_perm(hw, hw, sel);  // dup needed half
            AFrag a;
            #pragma unroll
            for (int p2 = 0; p2 < 4; ++p2)
                a.h2[p2] = hv.f * xp[m][p2].f;                 // v_pk_mul_f16
            #pragma unroll
            for (int nt = 0; nt < 3; ++nt)
                acc[m][nt] = __builtin_amdgcn_mfma_f32_16x16x32_f16(a.v, b[nt].v, acc[m][nt], 0, 0, 0);
        }
    }

    // ---- epilogue: C layout col=r_, row=q*4+i; write 96-B f16 rows at pos ----
    unsigned int* mixu = (unsigned int*)mixs;
    #pragma unroll
    for (int m = 0; m < 4; ++m) {
        #pragma unroll
        for (int i = 0; i < 4; ++i) {
            int e = ebase + m * 16 + q * 4 + i;
            if (e < E) {
                int p = pos[e];
                HW pr; pr.g = __builtin_amdgcn_cvt_pkrtz(acc[m][0][i], acc[m][1][i]);
                mixu[(size_t)p * 24 + r_] = pr.u;
                mixs[(size_t)p * 48 + 32 + r_] = (_Float16)acc[m][2][i];
            }
        }
    }
}

// ------------------------------ gather -------------------------------------
// mix (96-B f16 rows) and sh (20-B f16 rows) in CSR order -> linear reads.

__global__ __launch_bounds__(256)
void gather_kernel(const _Float16* __restrict__ mixs, const _Float16* __restrict__ shs,
                   const int* __restrict__ offs,
                   const float* __restrict__ nf, const float* __restrict__ Wsi,
                   float* __restrict__ out, int N) {
    int node = blockIdx.x * 4 + (threadIdx.x >> 6);
    if (node >= N) return;
    int lane = threadIdx.x & 63;

    // channel c -> (f16 half-index within 48-half mix row, sh index)
    auto chmap = [](int c, int& hi, int& si) {
        if (c < 16)      { hi = 2 * c;           si = 0; }
        else if (c < 64) { int t = c - 16; hi = 2 * (t / 3) + 1; si = 1 + t % 3; }
        else             { int t = c - 64; hi = 32 + t / 5;      si = 4 + t % 5; }
    };
    int hi0, si0, hi1, si1, hi2 = 0, si2 = 0;
    chmap(lane, hi0, si0);
    chmap(lane + 64, hi1, si1);
    if (lane < 16) chmap(lane + 128, hi2, si2);

    float a0 = 0.f, a1 = 0.f, a2 = 0.f;
    float b0 = 0.f, b1 = 0.f, b2 = 0.f;
    float c0 = 0.f, c1 = 0.f, c2 = 0.f;
    float d0 = 0.f, d1 = 0.f, d2 = 0.f;
    int off = offs[node], end = offs[node + 1];
    int i = off;
    for (; i + 3 < end; i += 4) {
        const _Float16* m0 = mixs + (size_t)i * 48;
        const _Float16* m1 = m0 + 48;
        const _Float16* m2 = m0 + 96;
        const _Float16* m3 = m0 + 144;
        const _Float16* s0 = shs + (size_t)i * 10;
        const _Float16* s1 = s0 + 10;
        const _Float16* s2 = s0 + 20;
        const _Float16* s3 = s0 + 30;
        a0 = fmaf((float)m0[hi0], (float)s0[si0], a0);
        b0 = fmaf((float)m1[hi0], (float)s1[si0], b0);
        c0 = fmaf((float)m2[hi0], (float)s2[si0], c0);
        d0 = fmaf((float)m3[hi0], (float)s3[si0], d0);
        a1 = fmaf((float)m0[hi1], (float)s0[si1], a1);
        b1 = fmaf((float)m1[hi1], (float)s1[si1], b1);
        c1 = fmaf((float)m2[hi1], (float)s2[si1], c1);
        d1 = fmaf((float)m3[hi1], (float)s3[si1], d1);
        if (lane < 16) {
            a2 = fmaf((float)m0[hi2], (float)s0[si2], a2);
            b2 = fmaf((float)m1[hi2], (float)s1[si2], b2);
            c2 = fmaf((float)m2[hi2], (float)s2[si2], c2);
            d2 = fmaf((float)m3[hi2], (float)s3[si2], d2);
        }
    }
    for (; i < end; ++i) {
        const _Float16* m0 = mixs + (size_t)i * 48;
        const _Float16* s0 = shs + (size_t)i * 10;
        a0 = fmaf((float)m0[hi0], (float)s0[si0], a0);
        a1 = fmaf((float)m0[hi1], (float)s0[si1], a1);
        if (lane < 16) a2 = fmaf((float)m0[hi2], (float)s0[si2], a2);
    }
    a0 += b0 + c0 + d0;
    a1 += b1 + c1 + d1;
    a2 += b2 + c2 + d2;

    if (lane < 16) {   // self-interaction, 0e->0e only
        const float* xr = nf + (size_t)node * 16;
        float si = 0.0f;
        #pragma unroll
        for (int u = 0; u < 16; ++u)
            si = fmaf(xr[u], Wsi[u * 16 + lane], si);
        a0 = fmaf(si, 0.25f, a0);
    }

    float* orow = out + (size_t)node * 144;
    orow[lane] = a0;
    orow[lane + 64] = a1;
    if (lane < 16) orow[lane + 128] = a2;
}

// ------------------------- fallback (atomic path) --------------------------

__global__ __launch_bounds__(256)
void si_init_kernel(const float* __restrict__ nf, const float* __restrict__ Wsi,
                    float* __restrict__ out, int N) {
    int t = blockIdx.x * blockDim.x + threadIdx.x;
    int total = N * 144;
    if (t >= total) return;
    int n = t / 144;
    int c = t - n * 144;
    float val = 0.0f;
    if (c < 16) {
        const float* xr = nf + n * 16;
        #pragma unroll
        for (int u = 0; u < 16; ++u)
            val = fmaf(xr[u], Wsi[u * 16 + c], val);
        val *= 0.25f;
    }
    out[t] = val;
}

__global__ __launch_bounds__(256)
void edge_kernel_atomic(const float* __restrict__ nf, const int* __restrict__ ei,
                        const float* __restrict__ sh, const float* __restrict__ radial,
                        const float* __restrict__ W1, const float* __restrict__ W2,
                        float* __restrict__ out, int E) {
    int e = blockIdx.x * blockDim.x + threadIdx.x;
    if (e >= E) return;
    int src = ei[e];
    int dst = ei[E + e];
    float r[16], x[16];
    #pragma unroll
    for (int u = 0; u < 16; ++u) r[u] = radial[e * 16 + u] * 0.25f;
    #pragma unroll
    for (int u = 0; u < 16; ++u) x[u] = nf[src * 16 + u] * 0.03125f;
    float acc[48];
    #pragma unroll
    for (int j = 0; j < 48; ++j) acc[j] = 0.0f;
    for (int k = 0; k < 64; ++k) {
        float z = 0.0f;
        #pragma unroll
        for (int u = 0; u < 16; ++u) z = fmaf(r[u], W1[u * 64 + k], z);
        float hk = z / (1.0f + __expf(-z));
        const float* w2k = W2 + k * 768;
        #pragma unroll 4
        for (int u = 0; u < 16; ++u) {
            float p = hk * x[u];
            const float* w = w2k + u * 16;
            #pragma unroll
            for (int l = 0; l < 3; ++l)
                #pragma unroll
                for (int v = 0; v < 16; ++v)
                    acc[l * 16 + v] = fmaf(p, w[l * 256 + v], acc[l * 16 + v]);
        }
    }
    const float* she = sh + e * 9;
    float* orow = out + (long)dst * 144;
    #pragma unroll
    for (int v = 0; v < 16; ++v) atomicAdd(&orow[v], acc[v] * she[0]);
    #pragma unroll
    for (int v = 0; v < 16; ++v)
        for (int m = 0; m < 3; ++m)
            atomicAdd(&orow[16 + v * 3 + m], acc[16 + v] * she[1 + m]);
    #pragma unroll
    for (int v = 0; v < 16; ++v)
        for (int m = 0; m < 5; ++m)
            atomicAdd(&orow[64 + v * 5 + m], acc[32 + v] * she[4 + m]);
}

// ---------------------------------------------------------------------------

extern "C" void kernel_launch(void* const* d_in, const int* in_sizes, int n_in,
                              void* d_out, int out_size, void* d_ws, size_t ws_size,
                              hipStream_t stream) {
    const float* nf     = (const float*)d_in[0];
    const int*   ei     = (const int*)  d_in[1];
    const float* sh     = (const float*)d_in[2];
    const float* radial = (const float*)d_in[3];
    const float* W1     = (const float*)d_in[4];
    const float* W2     = (const float*)d_in[5];
    const float* Wsi    = (const float*)d_in[6];
    float* out = (float*)d_out;

    const int N = in_sizes[0] / 16;
    const int E = in_sizes[1] / 2;

    size_t mix_bytes  = (size_t)E * 48 * sizeof(_Float16);   // 96-B f16 rows
    size_t offs_bytes = (size_t)(N + 1) * sizeof(int);
    size_t curs_bytes = (size_t)N * sizeof(int);
    size_t pos_bytes  = (size_t)E * sizeof(int);
    size_t shs_bytes  = (size_t)E * 10 * sizeof(_Float16);   // 20-B f16 sh rows
    size_t bfrag_off  = (mix_bytes + offs_bytes + curs_bytes + pos_bytes + shs_bytes + 127) & ~(size_t)127;
    size_t bfrag_bytes = 96 * 512 * sizeof(_Float16);        // 96 KB
    size_t need = bfrag_off + bfrag_bytes;

    if (ws_size < need) {
        int total = N * 144;
        hipLaunchKernelGGL(si_init_kernel, dim3((total + 255) / 256), dim3(256), 0, stream,
                           nf, Wsi, out, N);
        hipLaunchKernelGGL(edge_kernel_atomic, dim3((E + 255) / 256), dim3(256), 0, stream,
                           nf, ei, sh, radial, W1, W2, out, E);
        return;
    }

    char* wsb = (char*)d_ws;
    _Float16* mixs = (_Float16*)wsb;
    int*   offs = (int*)(wsb + mix_bytes);
    int*   curs = (int*)(wsb + mix_bytes + offs_bytes);
    int*   pos  = (int*)(wsb + mix_bytes + offs_bytes + curs_bytes);
    _Float16* shs = (_Float16*)(wsb + mix_bytes + offs_bytes + curs_bytes + pos_bytes);
    _Float16* bfrag = (_Float16*)(wsb + bfrag_off);

    (void)hipMemsetAsync(offs, 0, offs_bytes + curs_bytes, stream);

    int eb = (E + 255) / 256;
    hipLaunchKernelGGL(prep_kernel, dim3(eb), dim3(256), 0, stream,
                       W2, bfrag, ei, offs, E);
    hipLaunchKernelGGL(scan_kernel, dim3(1), dim3(1024), 0, stream, offs, N + 1);
    hipLaunchKernelGGL(scatter_kernel, dim3(eb), dim3(256), 0, stream,
                       ei, sh, offs, curs, pos, shs, E);
    hipLaunchKernelGGL(edge_mfma_kernel, dim3(eb), dim3(256), 0, stream,
                       nf, ei, radial, W1, bfrag, pos, mixs, E);
    hipLaunchKernelGGL(gather_kernel, dim3((N + 3) / 4), dim3(256), 0, stream,
                       mixs, shs, offs, nf, Wsi, out, N);
}

// Round 13
// 159.864 us; speedup vs baseline: 1.6602x; 1.1044x over previous
//
#include <hip/hip_runtime.h>

// ---------------------------------------------------------------------------
// SE3 conv layer, 5-dispatch pipeline:
//   memset -> prep (bfrag f16 pack + dst histogram) -> scan
//   -> edge (CSR claim + sh pack + f16 MFMA contraction)
//   -> gather (linear segmented reduction + self-interaction)
// mix rows: 96 B f16 (16 u32 of (l0,l1) pairs + 16 f16 l2), CSR-ordered.
// ws: [ mix E*48 f16 | offs N+1 | curs N | shs E*10 f16 | bfrag 96KB ]
// R10 lesson: launch_bounds(256,5)+unroll4 -> VGPR spills (FETCH 19->124MB).
// R11 lesson: W1T via global "uniform" loads doesn't scalarize -> +19us;
//             stage W1 in LDS (ds_read broadcast is the reliable path).
// R9 lesson: CSR-claim must be lane-parallel (phase 0.5), NOT per-fragment
//            serial atomic+shfl in the epilogue.
// ---------------------------------------------------------------------------

typedef _Float16 f16x2 __attribute__((ext_vector_type(2)));
typedef _Float16 f16x8 __attribute__((ext_vector_type(8)));
typedef __fp16  g16x2 __attribute__((ext_vector_type(2)));   // cvt_pkrtz result type
typedef float f32x4 __attribute__((ext_vector_type(4)));

union AFrag { unsigned int u[4]; f16x2 h2[4]; f16x8 v; };
union BFrag { uint4 u4; f16x8 v; };
union HW { g16x2 g; f16x2 f; unsigned int u; };

// ------------------- prep: bfrag pack + dst histogram -----------------------
// Bfrag[f][lane][j], f = ks*3+nt, ku = ks*32 + (lane>>4)*8 + j,
// k=ku>>4, u=ku&15, n = nt*16 + (lane&15), l=n>>4, v=n&15; val = W2/32.

__global__ __launch_bounds__(256)
void prep_kernel(const float* __restrict__ W2, _Float16* __restrict__ bfrag,
                 const int* __restrict__ ei, int* __restrict__ counts, int E) {
    int t = blockIdx.x * 256 + threadIdx.x;
    if (t < E) atomicAdd(&counts[ei[E + t] + 1], 1);
    if (t < 96 * 512) {
        int f = t >> 9;
        int rr = t & 511;
        int lane = rr >> 3, j = rr & 7;
        int ks = f / 3, nt = f - 3 * ks;
        int q = lane >> 4, c = lane & 15;
        int ku = ks * 32 + q * 8 + j;
        int k = ku >> 4, u = ku & 15;
        int n = nt * 16 + c;
        int l = n >> 4, v = n & 15;
        float val = W2[(size_t)k * 768 + l * 256 + u * 16 + v] * 0.03125f;
        bfrag[t] = (_Float16)val;
    }
}

// chunk-serial scan: 1 block, each thread owns ceil(n/1024) contiguous elems.
__global__ __launch_bounds__(1024)
void scan_kernel(int* __restrict__ data, int n) {
    __shared__ int wsum[16];
    int tid = threadIdx.x, lane = tid & 63, wid = tid >> 6;
    int ch = (n + 1023) >> 10;
    int beg = tid * ch;
    int end = beg + ch; if (end > n) end = n;

    int s = 0;
    for (int i = beg; i < end; ++i) s += data[i];

    int v = s;
    #pragma unroll
    for (int off = 1; off < 64; off <<= 1) {
        int t = __shfl_up(v, off, 64);
        if (lane >= off) v += t;
    }
    if (lane == 63) wsum[wid] = v;
    __syncthreads();
    if (wid == 0 && lane < 16) {
        int w = wsum[lane];
        #pragma unroll
        for (int off = 1; off < 16; off <<= 1) {
            int t = __shfl_up(w, off, 16);
            if (lane >= off) w += t;
        }
        wsum[lane] = w;
    }
    __syncthreads();
    int run = (v - s) + (wid > 0 ? wsum[wid - 1] : 0);   // exclusive offset
    for (int i = beg; i < end; ++i) {
        run += data[i];
        data[i] = run;
    }
}

// --------------------------- MFMA edge kernel ------------------------------
// block = 256 = 4 waves; wave owns 64 edges (4 M-tiles of 16).
// Phase 0.5 (lane = edge): claim CSR slot, stash p in LDS, pack sh row.

__global__ __launch_bounds__(256, 4)
void edge_mfma_kernel(const float* __restrict__ nf, const int* __restrict__ ei,
                      const float* __restrict__ radial, const float* __restrict__ W1,
                      const float* __restrict__ sh,
                      const _Float16* __restrict__ bfrag,
                      const int* __restrict__ offs, int* __restrict__ curs,
                      _Float16* __restrict__ mixs, _Float16* __restrict__ shs, int E) {
    __shared__ unsigned int h_lds[4][64][32];   // f16 pairs (k=2t,2t+1), XOR-swizzled
    __shared__ float w1t[64][16];               // W1^T, pre-scaled by 1/4
    __shared__ int   p_lds[4][64];              // CSR position per edge

    int tid = threadIdx.x;

    // stage W1^T (scaled) into LDS once per block (ds_read broadcasts later)
    for (int idx = tid; idx < 1024; idx += 256) {
        int k = idx >> 4, u = idx & 15;
        w1t[k][u] = W1[u * 64 + k] * 0.25f;
    }
    __syncthreads();

    int wave = tid >> 6;
    int lane = tid & 63;
    int r_ = lane & 15;
    int q  = lane >> 4;
    int qh = q >> 1;                 // which half of the h-pair this lane needs
    int ul = (q & 1) * 8;            // u base for A-frag
    unsigned int sel = qh ? 0x03020302u : 0x01000100u;   // v_perm dup selector

    int ebase = blockIdx.x * 256 + wave * 64;

    // ---- phase 0: x rows for the wave's 4 M-tiles (issue early), f16 pack ----
    HW xp[4][4];
    #pragma unroll
    for (int m = 0; m < 4; ++m) {
        int e = ebase + m * 16 + r_; if (e >= E) e = E - 1;
        int src = ei[e];
        const float* xpp = nf + (size_t)src * 16 + ul;
        float4 a = *(const float4*)xpp;
        float4 b = *(const float4*)(xpp + 4);
        xp[m][0].g = __builtin_amdgcn_cvt_pkrtz(a.x, a.y);
        xp[m][1].g = __builtin_amdgcn_cvt_pkrtz(a.z, a.w);
        xp[m][2].g = __builtin_amdgcn_cvt_pkrtz(b.x, b.y);
        xp[m][3].g = __builtin_amdgcn_cvt_pkrtz(b.z, b.w);
    }

    // ---- phase 0.5: lane = edge; claim CSR slot + pack sh row (parallel) ----
    {
        int e = ebase + lane;
        if (e < E) {
            int dst = ei[E + e];
            int p = offs[dst] + atomicAdd(&curs[dst], 1);
            p_lds[wave][lane] = p;
            const float* s = sh + (size_t)e * 9;
            float4 s03 = *(const float4*)s;
            float4 s47 = *(const float4*)(s + 4);
            float s8 = s[8];
            unsigned int* d = (unsigned int*)(shs + (size_t)p * 10);
            HW w0, w1, w2, w3, w4;
            w0.g = __builtin_amdgcn_cvt_pkrtz(s03.x, s03.y);
            w1.g = __builtin_amdgcn_cvt_pkrtz(s03.z, s03.w);
            w2.g = __builtin_amdgcn_cvt_pkrtz(s47.x, s47.y);
            w3.g = __builtin_amdgcn_cvt_pkrtz(s47.z, s47.w);
            w4.g = __builtin_amdgcn_cvt_pkrtz(s8, 0.0f);
            d[0] = w0.u; d[1] = w1.u; d[2] = w2.u; d[3] = w3.u; d[4] = w4.u;
        }
    }

    // ---- phase 1: lane = edge; k-loop with W1^T broadcast reads from LDS ----
    {
        int e = ebase + lane; if (e >= E) e = E - 1;
        const float* rp = radial + (size_t)e * 16;
        float4 r0 = *(const float4*)(rp);
        float4 r1 = *(const float4*)(rp + 4);
        float4 r2 = *(const float4*)(rp + 8);
        float4 r3 = *(const float4*)(rp + 12);
        int swz = lane & 31;
        float hprev = 0.0f;
        #pragma unroll 8
        for (int k = 0; k < 64; ++k) {
            const float4* wr = (const float4*)(&w1t[k][0]);
            float4 w0 = wr[0], w1v = wr[1], w2v = wr[2], w3v = wr[3];
            float z = r0.x * w0.x;
            z = fmaf(r0.y, w0.y, z);  z = fmaf(r0.z, w0.z, z);  z = fmaf(r0.w, w0.w, z);
            z = fmaf(r1.x, w1v.x, z); z = fmaf(r1.y, w1v.y, z); z = fmaf(r1.z, w1v.z, z); z = fmaf(r1.w, w1v.w, z);
            z = fmaf(r2.x, w2v.x, z); z = fmaf(r2.y, w2v.y, z); z = fmaf(r2.z, w2v.z, z); z = fmaf(r2.w, w2v.w, z);
            z = fmaf(r3.x, w3v.x, z); z = fmaf(r3.y, w3v.y, z); z = fmaf(r3.z, w3v.z, z); z = fmaf(r3.w, w3v.w, z);
            float h = z * __builtin_amdgcn_rcpf(1.0f + __expf(-z));   // silu
            if (k & 1) {
                HW w; w.g = __builtin_amdgcn_cvt_pkrtz(hprev, h);     // (k-1, k)
                h_lds[wave][lane][(k >> 1) ^ swz] = w.u;
            } else {
                hprev = h;
            }
        }
    }
    // h_lds/p_lds are per-wave private; within-wave program order suffices.

    // ---- phase 2: K-loop, 32 steps of K=32 ----
    f32x4 acc[4][3];
    #pragma unroll
    for (int m = 0; m < 4; ++m)
        #pragma unroll
        for (int nt = 0; nt < 3; ++nt)
            acc[m][nt] = (f32x4){0.f, 0.f, 0.f, 0.f};

    #pragma unroll 2
    for (int ks = 0; ks < 32; ++ks) {
        BFrag b[3];
        #pragma unroll
        for (int nt = 0; nt < 3; ++nt)
            b[nt].u4 = *(const uint4*)(bfrag + (size_t)(ks * 3 + nt) * 512 + lane * 8);
        #pragma unroll
        for (int m = 0; m < 4; ++m) {
            int el = m * 16 + r_;
            unsigned int hw = h_lds[wave][el][ks ^ (el & 31)];
            HW hv; hv.u = __builtin_amdgcn_perm(hw, hw, sel);  // dup needed half
            AFrag a;
            #pragma unroll
            for (int p2 = 0; p2 < 4; ++p2)
                a.h2[p2] = hv.f * xp[m][p2].f;                 // v_pk_mul_f16
            #pragma unroll
            for (int nt = 0; nt < 3; ++nt)
                acc[m][nt] = __builtin_amdgcn_mfma_f32_16x16x32_f16(a.v, b[nt].v, acc[m][nt], 0, 0, 0);
        }
    }

    // ---- epilogue: C layout col=r_, row=q*4+i; write 96-B f16 rows at p ----
    unsigned int* mixu = (unsigned int*)mixs;
    #pragma unroll
    for (int m = 0; m < 4; ++m) {
        #pragma unroll
        for (int i = 0; i < 4; ++i) {
            int e = ebase + m * 16 + q * 4 + i;
            if (e < E) {
                int p = p_lds[wave][m * 16 + q * 4 + i];
                HW pr; pr.g = __builtin_amdgcn_cvt_pkrtz(acc[m][0][i], acc[m][1][i]);
                mixu[(size_t)p * 24 + r_] = pr.u;
                mixs[(size_t)p * 48 + 32 + r_] = (_Float16)acc[m][2][i];
            }
        }
    }
}

// ------------------------------ gather -------------------------------------
// mix (96-B f16 rows) and sh (20-B f16 rows) in CSR order -> linear reads.

__global__ __launch_bounds__(256)
void gather_kernel(const _Float16* __restrict__ mixs, const _Float16* __restrict__ shs,
                   const int* __restrict__ offs,
                   const float* __restrict__ nf, const float* __restrict__ Wsi,
                   float* __restrict__ out, int N) {
    int node = blockIdx.x * 4 + (threadIdx.x >> 6);
    if (node >= N) return;
    int lane = threadIdx.x & 63;

    // channel c -> (f16 half-index within 48-half mix row, sh index)
    auto chmap = [](int c, int& hi, int& si) {
        if (c < 16)      { hi = 2 * c;           si = 0; }
        else if (c < 64) { int t = c - 16; hi = 2 * (t / 3) + 1; si = 1 + t % 3; }
        else             { int t = c - 64; hi = 32 + t / 5;      si = 4 + t % 5; }
    };
    int hi0, si0, hi1, si1, hi2 = 0, si2 = 0;
    chmap(lane, hi0, si0);
    chmap(lane + 64, hi1, si1);
    if (lane < 16) chmap(lane + 128, hi2, si2);

    float a0 = 0.f, a1 = 0.f, a2 = 0.f;
    float b0 = 0.f, b1 = 0.f, b2 = 0.f;
    float c0 = 0.f, c1 = 0.f, c2 = 0.f;
    float d0 = 0.f, d1 = 0.f, d2 = 0.f;
    int off = offs[node], end = offs[node + 1];
    int i = off;
    for (; i + 3 < end; i += 4) {
        const _Float16* m0 = mixs + (size_t)i * 48;
        const _Float16* m1 = m0 + 48;
        const _Float16* m2 = m0 + 96;
        const _Float16* m3 = m0 + 144;
        const _Float16* s0 = shs + (size_t)i * 10;
        const _Float16* s1 = s0 + 10;
        const _Float16* s2 = s0 + 20;
        const _Float16* s3 = s0 + 30;
        a0 = fmaf((float)m0[hi0], (float)s0[si0], a0);
        b0 = fmaf((float)m1[hi0], (float)s1[si0], b0);
        c0 = fmaf((float)m2[hi0], (float)s2[si0], c0);
        d0 = fmaf((float)m3[hi0], (float)s3[si0], d0);
        a1 = fmaf((float)m0[hi1], (float)s0[si1], a1);
        b1 = fmaf((float)m1[hi1], (float)s1[si1], b1);
        c1 = fmaf((float)m2[hi1], (float)s2[si1], c1);
        d1 = fmaf((float)m3[hi1], (float)s3[si1], d1);
        if (lane < 16) {
            a2 = fmaf((float)m0[hi2], (float)s0[si2], a2);
            b2 = fmaf((float)m1[hi2], (float)s1[si2], b2);
            c2 = fmaf((float)m2[hi2], (float)s2[si2], c2);
            d2 = fmaf((float)m3[hi2], (float)s3[si2], d2);
        }
    }
    for (; i < end; ++i) {
        const _Float16* m0 = mixs + (size_t)i * 48;
        const _Float16* s0 = shs + (size_t)i * 10;
        a0 = fmaf((float)m0[hi0], (float)s0[si0], a0);
        a1 = fmaf((float)m0[hi1], (float)s0[si1], a1);
        if (lane < 16) a2 = fmaf((float)m0[hi2], (float)s0[si2], a2);
    }
    a0 += b0 + c0 + d0;
    a1 += b1 + c1 + d1;
    a2 += b2 + c2 + d2;

    if (lane < 16) {   // self-interaction, 0e->0e only
        const float* xr = nf + (size_t)node * 16;
        float si = 0.0f;
        #pragma unroll
        for (int u = 0; u < 16; ++u)
            si = fmaf(xr[u], Wsi[u * 16 + lane], si);
        a0 = fmaf(si, 0.25f, a0);
    }

    float* orow = out + (size_t)node * 144;
    orow[lane] = a0;
    orow[lane + 64] = a1;
    if (lane < 16) orow[lane + 128] = a2;
}

// ------------------------- fallback (atomic path) --------------------------

__global__ __launch_bounds__(256)
void si_init_kernel(const float* __restrict__ nf, const float* __restrict__ Wsi,
                    float* __restrict__ out, int N) {
    int t = blockIdx.x * blockDim.x + threadIdx.x;
    int total = N * 144;
    if (t >= total) return;
    int n = t / 144;
    int c = t - n * 144;
    float val = 0.0f;
    if (c < 16) {
        const float* xr = nf + n * 16;
        #pragma unroll
        for (int u = 0; u < 16; ++u)
            val = fmaf(xr[u], Wsi[u * 16 + c], val);
        val *= 0.25f;
    }
    out[t] = val;
}

__global__ __launch_bounds__(256)
void edge_kernel_atomic(const float* __restrict__ nf, const int* __restrict__ ei,
                        const float* __restrict__ sh, const float* __restrict__ radial,
                        const float* __restrict__ W1, const float* __restrict__ W2,
                        float* __restrict__ out, int E) {
    int e = blockIdx.x * blockDim.x + threadIdx.x;
    if (e >= E) return;
    int src = ei[e];
    int dst = ei[E + e];
    float r[16], x[16];
    #pragma unroll
    for (int u = 0; u < 16; ++u) r[u] = radial[e * 16 + u] * 0.25f;
    #pragma unroll
    for (int u = 0; u < 16; ++u) x[u] = nf[src * 16 + u] * 0.03125f;
    float acc[48];
    #pragma unroll
    for (int j = 0; j < 48; ++j) acc[j] = 0.0f;
    for (int k = 0; k < 64; ++k) {
        float z = 0.0f;
        #pragma unroll
        for (int u = 0; u < 16; ++u) z = fmaf(r[u], W1[u * 64 + k], z);
        float hk = z / (1.0f + __expf(-z));
        const float* w2k = W2 + k * 768;
        #pragma unroll 4
        for (int u = 0; u < 16; ++u) {
            float p = hk * x[u];
            const float* w = w2k + u * 16;
            #pragma unroll
            for (int l = 0; l < 3; ++l)
                #pragma unroll
                for (int v = 0; v < 16; ++v)
                    acc[l * 16 + v] = fmaf(p, w[l * 256 + v], acc[l * 16 + v]);
        }
    }
    const float* she = sh + e * 9;
    float* orow = out + (long)dst * 144;
    #pragma unroll
    for (int v = 0; v < 16; ++v) atomicAdd(&orow[v], acc[v] * she[0]);
    #pragma unroll
    for (int v = 0; v < 16; ++v)
        for (int m = 0; m < 3; ++m)
            atomicAdd(&orow[16 + v * 3 + m], acc[16 + v] * she[1 + m]);
    #pragma unroll
    for (int v = 0; v < 16; ++v)
        for (int m = 0; m < 5; ++m)
            atomicAdd(&orow[64 + v * 5 + m], acc[32 + v] * she[4 + m]);
}

// ---------------------------------------------------------------------------

extern "C" void kernel_launch(void* const* d_in, const int* in_sizes, int n_in,
                              void* d_out, int out_size, void* d_ws, size_t ws_size,
                              hipStream_t stream) {
    const float* nf     = (const float*)d_in[0];
    const int*   ei     = (const int*)  d_in[1];
    const float* sh     = (const float*)d_in[2];
    const float* radial = (const float*)d_in[3];
    const float* W1     = (const float*)d_in[4];
    const float* W2     = (const float*)d_in[5];
    const float* Wsi    = (const float*)d_in[6];
    float* out = (float*)d_out;

    const int N = in_sizes[0] / 16;
    const int E = in_sizes[1] / 2;

    size_t mix_bytes  = (size_t)E * 48 * sizeof(_Float16);   // 96-B f16 rows
    size_t offs_bytes = (size_t)(N + 1) * sizeof(int);
    size_t curs_bytes = (size_t)N * sizeof(int);
    size_t shs_bytes  = (size_t)E * 10 * sizeof(_Float16);   // 20-B f16 sh rows
    size_t bfrag_off  = (mix_bytes + offs_bytes + curs_bytes + shs_bytes + 127) & ~(size_t)127;
    size_t bfrag_bytes = 96 * 512 * sizeof(_Float16);        // 96 KB
    size_t need = bfrag_off + bfrag_bytes;

    if (ws_size < need) {
        int total = N * 144;
        hipLaunchKernelGGL(si_init_kernel, dim3((total + 255) / 256), dim3(256), 0, stream,
                           nf, Wsi, out, N);
        hipLaunchKernelGGL(edge_kernel_atomic, dim3((E + 255) / 256), dim3(256), 0, stream,
                           nf, ei, sh, radial, W1, W2, out, E);
        return;
    }

    char* wsb = (char*)d_ws;
    _Float16* mixs = (_Float16*)wsb;
    int*   offs = (int*)(wsb + mix_bytes);
    int*   curs = (int*)(wsb + mix_bytes + offs_bytes);
    _Float16* shs = (_Float16*)(wsb + mix_bytes + offs_bytes + curs_bytes);
    _Float16* bfrag = (_Float16*)(wsb + bfrag_off);

    (void)hipMemsetAsync(offs, 0, offs_bytes + curs_bytes, stream);

    int eb = (E + 255) / 256;
    hipLaunchKernelGGL(prep_kernel, dim3(eb), dim3(256), 0, stream,
                       W2, bfrag, ei, offs, E);
    hipLaunchKernelGGL(scan_kernel, dim3(1), dim3(1024), 0, stream, offs, N + 1);
    hipLaunchKernelGGL(edge_mfma_kernel, dim3(eb), dim3(256), 0, stream,
                       nf, ei, radial, W1, sh, bfrag, offs, curs, mixs, shs, E);
    hipLaunchKernelGGL(gather_kernel, dim3((N + 3) / 4), dim3(256), 0, stream,
                       mixs, shs, offs, nf, Wsi, out, N);
}

// Round 15
// 137.749 us; speedup vs baseline: 1.9268x; 1.1605x over previous
//
#include <hip/hip_runtime.h>

// ---------------------------------------------------------------------------
// SE3 conv layer, 5-dispatch pipeline:
//   memset -> prep (bfrag f16 pack + dst histogram) -> scan (int4, padded)
//   -> edge (CSR claim + sh pack + f16 MFMA contraction)
//   -> gather (linear segmented reduction, 8-deep unroll + self-interaction)
// mix rows: 96 B f16 (16 u32 of (l0,l1) pairs + 16 f16 l2), CSR-ordered.
// ws: [ mix E*48 f16 | offs pad32768 | curs N | shs E*10 f16 | bfrag 96KB ]
// R10 lesson: launch_bounds(256,5)+unroll4 -> VGPR spills (FETCH 19->124MB).
// R11 lesson: W1T via global "uniform" loads doesn't scalarize; LDS broadcast.
// R9 lesson: CSR-claim must be lane-parallel (phase 0.5), not epilogue-serial.
// R14 lesson: scan tail guard dropped real counts (node 29999 segment lost);
//             fix = zero-padded region + UNconditional int4 loads/stores.
// ---------------------------------------------------------------------------

typedef _Float16 f16x2 __attribute__((ext_vector_type(2)));
typedef _Float16 f16x8 __attribute__((ext_vector_type(8)));
typedef __fp16  g16x2 __attribute__((ext_vector_type(2)));   // cvt_pkrtz result type
typedef float f32x4 __attribute__((ext_vector_type(4)));

union AFrag { unsigned int u[4]; f16x2 h2[4]; f16x8 v; };
union BFrag { uint4 u4; f16x8 v; };
union HW { g16x2 g; f16x2 f; unsigned int u; };

// ------------------- prep: bfrag pack + dst histogram -----------------------

__global__ __launch_bounds__(256)
void prep_kernel(const float* __restrict__ W2, _Float16* __restrict__ bfrag,
                 const int* __restrict__ ei, int* __restrict__ counts, int E) {
    int t = blockIdx.x * 256 + threadIdx.x;
    if (t < E) atomicAdd(&counts[ei[E + t] + 1], 1);
    if (t < 96 * 512) {
        int f = t >> 9;
        int rr = t & 511;
        int lane = rr >> 3, j = rr & 7;
        int ks = f / 3, nt = f - 3 * ks;
        int q = lane >> 4, c = lane & 15;
        int ku = ks * 32 + q * 8 + j;
        int k = ku >> 4, u = ku & 15;
        int n = nt * 16 + c;
        int l = n >> 4, v = n & 15;
        float val = W2[(size_t)k * 768 + l * 256 + u * 16 + v] * 0.03125f;
        bfrag[t] = (_Float16)val;
    }
}

// int4-vectorized inclusive scan over a ZERO-PADDED region (n_pad % 32768 == 0).
// Pad elements are zero -> they just replicate the running total; nothing
// reads them. All loads/stores unconditional (R14's tail guard was the bug).
__global__ __launch_bounds__(1024)
void scan_kernel(int* __restrict__ data, int n_pad) {
    __shared__ int wsum[16];
    __shared__ int carry_s;
    int tid = threadIdx.x, lane = tid & 63, wid = tid >> 6;
    if (tid == 0) carry_s = 0;
    __syncthreads();
    for (int base = 0; base < n_pad; base += 32768) {
        int beg = base + tid * 32;
        int4 c0[8];
        #pragma unroll
        for (int j = 0; j < 8; ++j)
            c0[j] = *(const int4*)(data + beg + j * 4);
        int s = 0;
        #pragma unroll
        for (int j = 0; j < 8; ++j) s += c0[j].x + c0[j].y + c0[j].z + c0[j].w;

        int v = s;
        #pragma unroll
        for (int off = 1; off < 64; off <<= 1) {
            int t = __shfl_up(v, off, 64);
            if (lane >= off) v += t;
        }
        if (lane == 63) wsum[wid] = v;
        __syncthreads();
        if (wid == 0 && lane < 16) {
            int w = wsum[lane];
            #pragma unroll
            for (int off = 1; off < 16; off <<= 1) {
                int t = __shfl_up(w, off, 16);
                if (lane >= off) w += t;
            }
            wsum[lane] = w;
        }
        __syncthreads();
        int run = carry_s + (v - s) + (wid > 0 ? wsum[wid - 1] : 0);
        #pragma unroll
        for (int j = 0; j < 8; ++j) {
            int4 o;
            run += c0[j].x; o.x = run;
            run += c0[j].y; o.y = run;
            run += c0[j].z; o.z = run;
            run += c0[j].w; o.w = run;
            *(int4*)(data + beg + j * 4) = o;
        }
        __syncthreads();
        if (tid == 1023) carry_s = run;   // carry + tile total
        __syncthreads();
    }
}

// --------------------------- MFMA edge kernel ------------------------------
// block = 256 = 4 waves; wave owns 64 edges (4 M-tiles of 16).

__global__ __launch_bounds__(256, 4)
void edge_mfma_kernel(const float* __restrict__ nf, const int* __restrict__ ei,
                      const float* __restrict__ radial, const float* __restrict__ W1,
                      const float* __restrict__ sh,
                      const _Float16* __restrict__ bfrag,
                      const int* __restrict__ offs, int* __restrict__ curs,
                      _Float16* __restrict__ mixs, _Float16* __restrict__ shs, int E) {
    __shared__ unsigned int h_lds[4][64][32];   // f16 pairs (k=2t,2t+1), XOR-swizzled
    __shared__ float w1t[64][16];               // W1^T, pre-scaled by 1/4
    __shared__ int   p_lds[4][64];              // CSR position per edge

    int tid = threadIdx.x;

    for (int idx = tid; idx < 1024; idx += 256) {
        int k = idx >> 4, u = idx & 15;
        w1t[k][u] = W1[u * 64 + k] * 0.25f;
    }
    __syncthreads();

    int wave = tid >> 6;
    int lane = tid & 63;
    int r_ = lane & 15;
    int q  = lane >> 4;
    int qh = q >> 1;
    int ul = (q & 1) * 8;
    unsigned int sel = qh ? 0x03020302u : 0x01000100u;

    int ebase = blockIdx.x * 256 + wave * 64;

    // ---- phase 0: x rows for the wave's 4 M-tiles, f16 pack ----
    HW xp[4][4];
    #pragma unroll
    for (int m = 0; m < 4; ++m) {
        int e = ebase + m * 16 + r_; if (e >= E) e = E - 1;
        int src = ei[e];
        const float* xpp = nf + (size_t)src * 16 + ul;
        float4 a = *(const float4*)xpp;
        float4 b = *(const float4*)(xpp + 4);
        xp[m][0].g = __builtin_amdgcn_cvt_pkrtz(a.x, a.y);
        xp[m][1].g = __builtin_amdgcn_cvt_pkrtz(a.z, a.w);
        xp[m][2].g = __builtin_amdgcn_cvt_pkrtz(b.x, b.y);
        xp[m][3].g = __builtin_amdgcn_cvt_pkrtz(b.z, b.w);
    }

    // ---- phase 0.5: lane = edge; claim CSR slot + pack sh row ----
    {
        int e = ebase + lane;
        if (e < E) {
            int dst = ei[E + e];
            int p = offs[dst] + atomicAdd(&curs[dst], 1);
            p_lds[wave][lane] = p;
            const float* s = sh + (size_t)e * 9;
            float4 s03 = *(const float4*)s;
            float4 s47 = *(const float4*)(s + 4);
            float s8 = s[8];
            unsigned int* d = (unsigned int*)(shs + (size_t)p * 10);
            HW w0, w1, w2, w3, w4;
            w0.g = __builtin_amdgcn_cvt_pkrtz(s03.x, s03.y);
            w1.g = __builtin_amdgcn_cvt_pkrtz(s03.z, s03.w);
            w2.g = __builtin_amdgcn_cvt_pkrtz(s47.x, s47.y);
            w3.g = __builtin_amdgcn_cvt_pkrtz(s47.z, s47.w);
            w4.g = __builtin_amdgcn_cvt_pkrtz(s8, 0.0f);
            d[0] = w0.u; d[1] = w1.u; d[2] = w2.u; d[3] = w3.u; d[4] = w4.u;
        }
    }

    // ---- phase 1: lane = edge; k-loop with W1^T broadcast reads from LDS ----
    {
        int e = ebase + lane; if (e >= E) e = E - 1;
        const float* rp = radial + (size_t)e * 16;
        float4 r0 = *(const float4*)(rp);
        float4 r1 = *(const float4*)(rp + 4);
        float4 r2 = *(const float4*)(rp + 8);
        float4 r3 = *(const float4*)(rp + 12);
        int swz = lane & 31;
        float hprev = 0.0f;
        #pragma unroll 8
        for (int k = 0; k < 64; ++k) {
            const float4* wr = (const float4*)(&w1t[k][0]);
            float4 w0 = wr[0], w1v = wr[1], w2v = wr[2], w3v = wr[3];
            float z = r0.x * w0.x;
            z = fmaf(r0.y, w0.y, z);  z = fmaf(r0.z, w0.z, z);  z = fmaf(r0.w, w0.w, z);
            z = fmaf(r1.x, w1v.x, z); z = fmaf(r1.y, w1v.y, z); z = fmaf(r1.z, w1v.z, z); z = fmaf(r1.w, w1v.w, z);
            z = fmaf(r2.x, w2v.x, z); z = fmaf(r2.y, w2v.y, z); z = fmaf(r2.z, w2v.z, z); z = fmaf(r2.w, w2v.w, z);
            z = fmaf(r3.x, w3v.x, z); z = fmaf(r3.y, w3v.y, z); z = fmaf(r3.z, w3v.z, z); z = fmaf(r3.w, w3v.w, z);
            float h = z * __builtin_amdgcn_rcpf(1.0f + __expf(-z));   // silu
            if (k & 1) {
                HW w; w.g = __builtin_amdgcn_cvt_pkrtz(hprev, h);
                h_lds[wave][lane][(k >> 1) ^ swz] = w.u;
            } else {
                hprev = h;
            }
        }
    }

    // ---- phase 2: K-loop, 32 steps of K=32 ----
    f32x4 acc[4][3];
    #pragma unroll
    for (int m = 0; m < 4; ++m)
        #pragma unroll
        for (int nt = 0; nt < 3; ++nt)
            acc[m][nt] = (f32x4){0.f, 0.f, 0.f, 0.f};

    #pragma unroll 2
    for (int ks = 0; ks < 32; ++ks) {
        BFrag b[3];
        #pragma unroll
        for (int nt = 0; nt < 3; ++nt)
            b[nt].u4 = *(const uint4*)(bfrag + (size_t)(ks * 3 + nt) * 512 + lane * 8);
        #pragma unroll
        for (int m = 0; m < 4; ++m) {
            int el = m * 16 + r_;
            unsigned int hw = h_lds[wave][el][ks ^ (el & 31)];
            HW hv; hv.u = __builtin_amdgcn_perm(hw, hw, sel);
            AFrag a;
            #pragma unroll
            for (int p2 = 0; p2 < 4; ++p2)
                a.h2[p2] = hv.f * xp[m][p2].f;
            #pragma unroll
            for (int nt = 0; nt < 3; ++nt)
                acc[m][nt] = __builtin_amdgcn_mfma_f32_16x16x32_f16(a.v, b[nt].v, acc[m][nt], 0, 0, 0);
        }
    }

    // ---- epilogue: C layout col=r_, row=q*4+i; write 96-B f16 rows at p ----
    unsigned int* mixu = (unsigned int*)mixs;
    #pragma unroll
    for (int m = 0; m < 4; ++m) {
        #pragma unroll
        for (int i = 0; i < 4; ++i) {
            int e = ebase + m * 16 + q * 4 + i;
            if (e < E) {
                int p = p_lds[wave][m * 16 + q * 4 + i];
                HW pr; pr.g = __builtin_amdgcn_cvt_pkrtz(acc[m][0][i], acc[m][1][i]);
                mixu[(size_t)p * 24 + r_] = pr.u;
                mixs[(size_t)p * 48 + 32 + r_] = (_Float16)acc[m][2][i];
            }
        }
    }
}

// ------------------------------ gather -------------------------------------
// mix (96-B f16 rows) and sh (20-B f16 rows) in CSR order -> linear reads.
// 8 independent accumulator groups -> 8 edges' loads in flight per wave.

__global__ __launch_bounds__(256)
void gather_kernel(const _Float16* __restrict__ mixs, const _Float16* __restrict__ shs,
                   const int* __restrict__ offs,
                   const float* __restrict__ nf, const float* __restrict__ Wsi,
                   float* __restrict__ out, int N) {
    int node = blockIdx.x * 4 + (threadIdx.x >> 6);
    if (node >= N) return;
    int lane = threadIdx.x & 63;

    auto chmap = [](int c, int& hi, int& si) {
        if (c < 16)      { hi = 2 * c;           si = 0; }
        else if (c < 64) { int t = c - 16; hi = 2 * (t / 3) + 1; si = 1 + t % 3; }
        else             { int t = c - 64; hi = 32 + t / 5;      si = 4 + t % 5; }
    };
    int hi0, si0, hi1, si1, hi2 = 0, si2 = 0;
    chmap(lane, hi0, si0);
    chmap(lane + 64, hi1, si1);
    if (lane < 16) chmap(lane + 128, hi2, si2);

    float g0[8], g1[8], g2[8];
    #pragma unroll
    for (int j = 0; j < 8; ++j) { g0[j] = 0.f; g1[j] = 0.f; g2[j] = 0.f; }

    int off = offs[node], end = offs[node + 1];
    int i = off;
    for (; i + 7 < end; i += 8) {
        #pragma unroll
        for (int j = 0; j < 8; ++j) {
            const _Float16* m = mixs + (size_t)(i + j) * 48;
            const _Float16* s = shs + (size_t)(i + j) * 10;
            g0[j] = fmaf((float)m[hi0], (float)s[si0], g0[j]);
            g1[j] = fmaf((float)m[hi1], (float)s[si1], g1[j]);
            if (lane < 16) g2[j] = fmaf((float)m[hi2], (float)s[si2], g2[j]);
        }
    }
    for (int j = 0; i < end; ++i, ++j) {
        const _Float16* m = mixs + (size_t)i * 48;
        const _Float16* s = shs + (size_t)i * 10;
        g0[j] = fmaf((float)m[hi0], (float)s[si0], g0[j]);
        g1[j] = fmaf((float)m[hi1], (float)s[si1], g1[j]);
        if (lane < 16) g2[j] = fmaf((float)m[hi2], (float)s[si2], g2[j]);
    }
    float a0 = (g0[0] + g0[1]) + (g0[2] + g0[3]) + ((g0[4] + g0[5]) + (g0[6] + g0[7]));
    float a1 = (g1[0] + g1[1]) + (g1[2] + g1[3]) + ((g1[4] + g1[5]) + (g1[6] + g1[7]));
    float a2 = (g2[0] + g2[1]) + (g2[2] + g2[3]) + ((g2[4] + g2[5]) + (g2[6] + g2[7]));

    if (lane < 16) {   // self-interaction, 0e->0e only
        const float* xr = nf + (size_t)node * 16;
        float si = 0.0f;
        #pragma unroll
        for (int u = 0; u < 16; ++u)
            si = fmaf(xr[u], Wsi[u * 16 + lane], si);
        a0 = fmaf(si, 0.25f, a0);
    }

    float* orow = out + (size_t)node * 144;
    orow[lane] = a0;
    orow[lane + 64] = a1;
    if (lane < 16) orow[lane + 128] = a2;
}

// ------------------------- fallback (atomic path) --------------------------

__global__ __launch_bounds__(256)
void si_init_kernel(const float* __restrict__ nf, const float* __restrict__ Wsi,
                    float* __restrict__ out, int N) {
    int t = blockIdx.x * blockDim.x + threadIdx.x;
    int total = N * 144;
    if (t >= total) return;
    int n = t / 144;
    int c = t - n * 144;
    float val = 0.0f;
    if (c < 16) {
        const float* xr = nf + n * 16;
        #pragma unroll
        for (int u = 0; u < 16; ++u)
            val = fmaf(xr[u], Wsi[u * 16 + c], val);
        val *= 0.25f;
    }
    out[t] = val;
}

__global__ __launch_bounds__(256)
void edge_kernel_atomic(const float* __restrict__ nf, const int* __restrict__ ei,
                        const float* __restrict__ sh, const float* __restrict__ radial,
                        const float* __restrict__ W1, const float* __restrict__ W2,
                        float* __restrict__ out, int E) {
    int e = blockIdx.x * blockDim.x + threadIdx.x;
    if (e >= E) return;
    int src = ei[e];
    int dst = ei[E + e];
    float r[16], x[16];
    #pragma unroll
    for (int u = 0; u < 16; ++u) r[u] = radial[e * 16 + u] * 0.25f;
    #pragma unroll
    for (int u = 0; u < 16; ++u) x[u] = nf[src * 16 + u] * 0.03125f;
    float acc[48];
    #pragma unroll
    for (int j = 0; j < 48; ++j) acc[j] = 0.0f;
    for (int k = 0; k < 64; ++k) {
        float z = 0.0f;
        #pragma unroll
        for (int u = 0; u < 16; ++u) z = fmaf(r[u], W1[u * 64 + k], z);
        float hk = z / (1.0f + __expf(-z));
        const float* w2k = W2 + k * 768;
        #pragma unroll 4
        for (int u = 0; u < 16; ++u) {
            float p = hk * x[u];
            const float* w = w2k + u * 16;
            #pragma unroll
            for (int l = 0; l < 3; ++l)
                #pragma unroll
                for (int v = 0; v < 16; ++v)
                    acc[l * 16 + v] = fmaf(p, w[l * 256 + v], acc[l * 16 + v]);
        }
    }
    const float* she = sh + e * 9;
    float* orow = out + (long)dst * 144;
    #pragma unroll
    for (int v = 0; v < 16; ++v) atomicAdd(&orow[v], acc[v] * she[0]);
    #pragma unroll
    for (int v = 0; v < 16; ++v)
        for (int m = 0; m < 3; ++m)
            atomicAdd(&orow[16 + v * 3 + m], acc[16 + v] * she[1 + m]);
    #pragma unroll
    for (int v = 0; v < 16; ++v)
        for (int m = 0; m < 5; ++m)
            atomicAdd(&orow[64 + v * 5 + m], acc[32 + v] * she[4 + m]);
}

// ---------------------------------------------------------------------------

extern "C" void kernel_launch(void* const* d_in, const int* in_sizes, int n_in,
                              void* d_out, int out_size, void* d_ws, size_t ws_size,
                              hipStream_t stream) {
    const float* nf     = (const float*)d_in[0];
    const int*   ei     = (const int*)  d_in[1];
    const float* sh     = (const float*)d_in[2];
    const float* radial = (const float*)d_in[3];
    const float* W1     = (const float*)d_in[4];
    const float* W2     = (const float*)d_in[5];
    const float* Wsi    = (const float*)d_in[6];
    float* out = (float*)d_out;

    const int N = in_sizes[0] / 16;
    const int E = in_sizes[1] / 2;

    // offs padded to a multiple of 32768 ints: scan does unconditional int4
    // loads/stores over the full padded (zeroed) region.
    int n_scan = N + 1;
    int n_pad  = (n_scan + 32767) & ~32767;

    size_t mix_bytes  = (size_t)E * 48 * sizeof(_Float16);   // 96-B f16 rows
    size_t offs_bytes = (size_t)n_pad * sizeof(int);
    size_t curs_bytes = (size_t)N * sizeof(int);
    size_t shs_bytes  = (size_t)E * 10 * sizeof(_Float16);   // 20-B f16 sh rows
    size_t bfrag_off  = (mix_bytes + offs_bytes + curs_bytes + shs_bytes + 127) & ~(size_t)127;
    size_t bfrag_bytes = 96 * 512 * sizeof(_Float16);        // 96 KB
    size_t need = bfrag_off + bfrag_bytes;

    if (ws_size < need) {
        int total = N * 144;
        hipLaunchKernelGGL(si_init_kernel, dim3((total + 255) / 256), dim3(256), 0, stream,
                           nf, Wsi, out, N);
        hipLaunchKernelGGL(edge_kernel_atomic, dim3((E + 255) / 256), dim3(256), 0, stream,
                           nf, ei, sh, radial, W1, W2, out, E);
        return;
    }

    char* wsb = (char*)d_ws;
    _Float16* mixs = (_Float16*)wsb;
    int*   offs = (int*)(wsb + mix_bytes);
    int*   curs = (int*)(wsb + mix_bytes + offs_bytes);
    _Float16* shs = (_Float16*)(wsb + mix_bytes + offs_bytes + curs_bytes);
    _Float16* bfrag = (_Float16*)(wsb + bfrag_off);

    (void)hipMemsetAsync(offs, 0, offs_bytes + curs_bytes, stream);

    int eb = (E + 255) / 256;
    hipLaunchKernelGGL(prep_kernel, dim3(eb), dim3(256), 0, stream,
                       W2, bfrag, ei, offs, E);
    hipLaunchKernelGGL(scan_kernel, dim3(1), dim3(1024), 0, stream, offs, n_pad);
    hipLaunchKernelGGL(edge_mfma_kernel, dim3(eb), dim3(256), 0, stream,
                       nf, ei, radial, W1, sh, bfrag, offs, curs, mixs, shs, E);
    hipLaunchKernelGGL(gather_kernel, dim3((N + 3) / 4), dim3(256), 0, stream,
                       mixs, shs, offs, nf, Wsi, out, N);
}

// Round 16
// 134.823 us; speedup vs baseline: 1.9686x; 1.0217x over previous
//
#include <hip/hip_runtime.h>

// ---------------------------------------------------------------------------
// SE3 conv layer, 5-dispatch pipeline:
//   memset -> prep (bfrag + w1frag f16 pack + dst histogram) -> scan (int4)
//   -> edge (CSR claim + sh pack + MFMA radial-MLP + f16 MFMA contraction)
//   -> gather (linear segmented reduction, 8-deep unroll + self-interaction)
// mix rows: 96 B f16 (16 u32 of (l0,l1) pairs + 16 f16 l2), CSR-ordered.
// ws: [ mix E*48 f16 | offs pad32768 | curs N | shs E*10 f16 | bfrag | w1frag ]
// R10 lesson: VGPR cap + wide unroll -> spills (FETCH 19->124MB). Watch FETCH.
// R11 lesson: "uniform" global loads don't scalarize; use LDS or MFMA.
// R9 lesson: CSR-claim must be lane-parallel, not epilogue-serial.
// R14 lesson: scan tail guard dropped counts; zero-padded unconditional int4.
// R16: phase-1 radial MLP via MFMA (kills 256 ds_read_b128/wave), LDS=32KB
//      exactly (p_lds -> register+shfl) for 5 blocks/CU.
// ---------------------------------------------------------------------------

typedef _Float16 f16x2 __attribute__((ext_vector_type(2)));
typedef _Float16 f16x8 __attribute__((ext_vector_type(8)));
typedef __fp16  g16x2 __attribute__((ext_vector_type(2)));   // cvt_pkrtz result type
typedef float f32x4 __attribute__((ext_vector_type(4)));

union AFrag { unsigned int u[4]; f16x2 h2[4]; f16x8 v; };
union BFrag { uint4 u4; f16x8 v; };
union HW { g16x2 g; f16x2 f; unsigned int u; };

// ----------- prep: bfrag pack + W1 frag pack + dst histogram ----------------
// Bfrag[f][lane][j], f = ks*3+nt, ku = ks*32 + (lane>>4)*8 + j,
// k=ku>>4, u=ku&15, n = nt*16 + (lane&15), l=n>>4, v=n&15; val = W2/32.
// W1frag[nt][lane][j]: B-frag for z = radial @ W1: col k = nt*16 + (lane&15),
// K-dim u = (lane>>4)*8 + j (u<16 real, scaled 1/4; u>=16 zero-pad).

__global__ __launch_bounds__(256)
void prep_kernel(const float* __restrict__ W2, const float* __restrict__ W1,
                 _Float16* __restrict__ bfrag, _Float16* __restrict__ w1frag,
                 const int* __restrict__ ei, int* __restrict__ counts, int E) {
    int t = blockIdx.x * 256 + threadIdx.x;
    if (t < E) atomicAdd(&counts[ei[E + t] + 1], 1);
    if (t < 96 * 512) {
        int f = t >> 9;
        int rr = t & 511;
        int lane = rr >> 3, j = rr & 7;
        int ks = f / 3, nt = f - 3 * ks;
        int q = lane >> 4, c = lane & 15;
        int ku = ks * 32 + q * 8 + j;
        int k = ku >> 4, u = ku & 15;
        int n = nt * 16 + c;
        int l = n >> 4, v = n & 15;
        float val = W2[(size_t)k * 768 + l * 256 + u * 16 + v] * 0.03125f;
        bfrag[t] = (_Float16)val;
    }
    if (t < 2048) {
        int nt = t >> 9, rr = t & 511;
        int lane = rr >> 3, j = rr & 7;
        int q = lane >> 4, c = lane & 15;
        int u = q * 8 + j;
        float val = (q < 2) ? W1[u * 64 + nt * 16 + c] * 0.25f : 0.0f;
        w1frag[t] = (_Float16)val;
    }
}

// int4-vectorized inclusive scan over a ZERO-PADDED region (n_pad % 32768 == 0).
__global__ __launch_bounds__(1024)
void scan_kernel(int* __restrict__ data, int n_pad) {
    __shared__ int wsum[16];
    __shared__ int carry_s;
    int tid = threadIdx.x, lane = tid & 63, wid = tid >> 6;
    if (tid == 0) carry_s = 0;
    __syncthreads();
    for (int base = 0; base < n_pad; base += 32768) {
        int beg = base + tid * 32;
        int4 c0[8];
        #pragma unroll
        for (int j = 0; j < 8; ++j)
            c0[j] = *(const int4*)(data + beg + j * 4);
        int s = 0;
        #pragma unroll
        for (int j = 0; j < 8; ++j) s += c0[j].x + c0[j].y + c0[j].z + c0[j].w;

        int v = s;
        #pragma unroll
        for (int off = 1; off < 64; off <<= 1) {
            int t = __shfl_up(v, off, 64);
            if (lane >= off) v += t;
        }
        if (lane == 63) wsum[wid] = v;
        __syncthreads();
        if (wid == 0 && lane < 16) {
            int w = wsum[lane];
            #pragma unroll
            for (int off = 1; off < 16; off <<= 1) {
                int t = __shfl_up(w, off, 16);
                if (lane >= off) w += t;
            }
            wsum[lane] = w;
        }
        __syncthreads();
        int run = carry_s + (v - s) + (wid > 0 ? wsum[wid - 1] : 0);
        #pragma unroll
        for (int j = 0; j < 8; ++j) {
            int4 o;
            run += c0[j].x; o.x = run;
            run += c0[j].y; o.y = run;
            run += c0[j].z; o.z = run;
            run += c0[j].w; o.w = run;
            *(int4*)(data + beg + j * 4) = o;
        }
        __syncthreads();
        if (tid == 1023) carry_s = run;
        __syncthreads();
    }
}

// --------------------------- MFMA edge kernel ------------------------------
// block = 256 = 4 waves; wave owns 64 edges (4 M-tiles of 16). Barrier-free.

__global__ __launch_bounds__(256, 4)
void edge_mfma_kernel(const float* __restrict__ nf, const int* __restrict__ ei,
                      const float* __restrict__ radial,
                      const _Float16* __restrict__ w1frag,
                      const float* __restrict__ sh,
                      const _Float16* __restrict__ bfrag,
                      const int* __restrict__ offs, int* __restrict__ curs,
                      _Float16* __restrict__ mixs, _Float16* __restrict__ shs, int E) {
    __shared__ unsigned int h_lds[4][64][32];   // f16 pairs (k=2t,2t+1), XOR-swizzled
    // exactly 32 KB LDS -> 5 blocks/CU

    int tid = threadIdx.x;
    int wave = tid >> 6;
    int lane = tid & 63;
    int r_ = lane & 15;
    int q  = lane >> 4;
    int qh = q >> 1;
    int ul = (q & 1) * 8;
    unsigned int sel = qh ? 0x03020302u : 0x01000100u;

    int ebase = blockIdx.x * 256 + wave * 64;

    // ---- phase 0: x rows for the wave's 4 M-tiles, f16 pack ----
    HW xp[4][4];
    #pragma unroll
    for (int m = 0; m < 4; ++m) {
        int e = ebase + m * 16 + r_; if (e >= E) e = E - 1;
        int src = ei[e];
        const float* xpp = nf + (size_t)src * 16 + ul;
        float4 a = *(const float4*)xpp;
        float4 b = *(const float4*)(xpp + 4);
        xp[m][0].g = __builtin_amdgcn_cvt_pkrtz(a.x, a.y);
        xp[m][1].g = __builtin_amdgcn_cvt_pkrtz(a.z, a.w);
        xp[m][2].g = __builtin_amdgcn_cvt_pkrtz(b.x, b.y);
        xp[m][3].g = __builtin_amdgcn_cvt_pkrtz(b.z, b.w);
    }

    // ---- phase 0.5: lane = edge; claim CSR slot (register p) + pack sh ----
    int p = 0;
    {
        int e = ebase + lane;
        if (e < E) {
            int dst = ei[E + e];
            p = offs[dst] + atomicAdd(&curs[dst], 1);
            const float* s = sh + (size_t)e * 9;
            float4 s03 = *(const float4*)s;
            float4 s47 = *(const float4*)(s + 4);
            float s8 = s[8];
            unsigned int* d = (unsigned int*)(shs + (size_t)p * 10);
            HW w0, w1, w2, w3, w4;
            w0.g = __builtin_amdgcn_cvt_pkrtz(s03.x, s03.y);
            w1.g = __builtin_amdgcn_cvt_pkrtz(s03.z, s03.w);
            w2.g = __builtin_amdgcn_cvt_pkrtz(s47.x, s47.y);
            w3.g = __builtin_amdgcn_cvt_pkrtz(s47.z, s47.w);
            w4.g = __builtin_amdgcn_cvt_pkrtz(s8, 0.0f);
            d[0] = w0.u; d[1] = w1.u; d[2] = w2.u; d[3] = w3.u; d[4] = w4.u;
        }
    }

    // ---- phase 1: radial MLP via MFMA: z[64e][64k] = radial @ W1frag ----
    // A: row = edge (r_), K = u (q*8+j; u>=16 zero). B: col = k, K = u.
    // C: col = k = nt*16 + r_, row = edge = q*4 + i. silu -> pair -> h_lds.
    {
        BFrag wf[4];
        #pragma unroll
        for (int nt = 0; nt < 4; ++nt)
            wf[nt].u4 = *(const uint4*)(w1frag + (size_t)nt * 512 + lane * 8);

        #pragma unroll
        for (int m = 0; m < 4; ++m) {
            AFrag ra;
            if (q < 2) {
                int e = ebase + m * 16 + r_; if (e >= E) e = E - 1;
                const float* rp = radial + (size_t)e * 16 + q * 8;
                float4 a = *(const float4*)rp;
                float4 b = *(const float4*)(rp + 4);
                HW t0, t1, t2, t3;
                t0.g = __builtin_amdgcn_cvt_pkrtz(a.x, a.y);
                t1.g = __builtin_amdgcn_cvt_pkrtz(a.z, a.w);
                t2.g = __builtin_amdgcn_cvt_pkrtz(b.x, b.y);
                t3.g = __builtin_amdgcn_cvt_pkrtz(b.z, b.w);
                ra.u[0] = t0.u; ra.u[1] = t1.u; ra.u[2] = t2.u; ra.u[3] = t3.u;
            } else {
                ra.u[0] = 0; ra.u[1] = 0; ra.u[2] = 0; ra.u[3] = 0;
            }
            #pragma unroll
            for (int nt = 0; nt < 4; ++nt) {
                f32x4 z4 = __builtin_amdgcn_mfma_f32_16x16x32_f16(
                    ra.v, wf[nt].v, (f32x4){0.f, 0.f, 0.f, 0.f}, 0, 0, 0);
                #pragma unroll
                for (int i = 0; i < 4; ++i) {
                    float z = z4[i];
                    float h = z * __builtin_amdgcn_rcpf(1.0f + __expf(-z));  // silu
                    float hn = __shfl_xor(h, 1);
                    if (!(r_ & 1)) {
                        int el = m * 16 + q * 4 + i;
                        HW w; w.g = __builtin_amdgcn_cvt_pkrtz(h, hn);  // (k, k+1)
                        h_lds[wave][el][((nt << 3) + (r_ >> 1)) ^ (el & 31)] = w.u;
                    }
                }
            }
        }
    }
    // h_lds per-wave private; within-wave program order suffices (no barrier)

    // ---- phase 2: K-loop, 32 steps of K=32 ----
    f32x4 acc[4][3];
    #pragma unroll
    for (int m = 0; m < 4; ++m)
        #pragma unroll
        for (int nt = 0; nt < 3; ++nt)
            acc[m][nt] = (f32x4){0.f, 0.f, 0.f, 0.f};

    #pragma unroll 2
    for (int ks = 0; ks < 32; ++ks) {
        BFrag b[3];
        #pragma unroll
        for (int nt = 0; nt < 3; ++nt)
            b[nt].u4 = *(const uint4*)(bfrag + (size_t)(ks * 3 + nt) * 512 + lane * 8);
        #pragma unroll
        for (int m = 0; m < 4; ++m) {
            int el = m * 16 + r_;
            unsigned int hw = h_lds[wave][el][ks ^ (el & 31)];
            HW hv; hv.u = __builtin_amdgcn_perm(hw, hw, sel);
            AFrag a;
            #pragma unroll
            for (int p2 = 0; p2 < 4; ++p2)
                a.h2[p2] = hv.f * xp[m][p2].f;
            #pragma unroll
            for (int nt = 0; nt < 3; ++nt)
                acc[m][nt] = __builtin_amdgcn_mfma_f32_16x16x32_f16(a.v, b[nt].v, acc[m][nt], 0, 0, 0);
        }
    }

    // ---- epilogue: C layout col=r_, row=q*4+i; p via shfl; 96-B f16 rows ----
    unsigned int* mixu = (unsigned int*)mixs;
    #pragma unroll
    for (int m = 0; m < 4; ++m) {
        #pragma unroll
        for (int i = 0; i < 4; ++i) {
            int el = m * 16 + q * 4 + i;
            int e = ebase + el;
            int pe = __shfl(p, el, 64);
            if (e < E) {
                HW pr; pr.g = __builtin_amdgcn_cvt_pkrtz(acc[m][0][i], acc[m][1][i]);
                mixu[(size_t)pe * 24 + r_] = pr.u;
                mixs[(size_t)pe * 48 + 32 + r_] = (_Float16)acc[m][2][i];
            }
        }
    }
}

// ------------------------------ gather -------------------------------------
// mix (96-B f16 rows) and sh (20-B f16 rows) in CSR order -> linear reads.

__global__ __launch_bounds__(256)
void gather_kernel(const _Float16* __restrict__ mixs, const _Float16* __restrict__ shs,
                   const int* __restrict__ offs,
                   const float* __restrict__ nf, const float* __restrict__ Wsi,
                   float* __restrict__ out, int N) {
    int node = blockIdx.x * 4 + (threadIdx.x >> 6);
    if (node >= N) return;
    int lane = threadIdx.x & 63;

    auto chmap = [](int c, int& hi, int& si) {
        if (c < 16)      { hi = 2 * c;           si = 0; }
        else if (c < 64) { int t = c - 16; hi = 2 * (t / 3) + 1; si = 1 + t % 3; }
        else             { int t = c - 64; hi = 32 + t / 5;      si = 4 + t % 5; }
    };
    int hi0, si0, hi1, si1, hi2 = 0, si2 = 0;
    chmap(lane, hi0, si0);
    chmap(lane + 64, hi1, si1);
    if (lane < 16) chmap(lane + 128, hi2, si2);

    float g0[8], g1[8], g2[8];
    #pragma unroll
    for (int j = 0; j < 8; ++j) { g0[j] = 0.f; g1[j] = 0.f; g2[j] = 0.f; }

    int off = offs[node], end = offs[node + 1];
    int i = off;
    for (; i + 7 < end; i += 8) {
        #pragma unroll
        for (int j = 0; j < 8; ++j) {
            const _Float16* m = mixs + (size_t)(i + j) * 48;
            const _Float16* s = shs + (size_t)(i + j) * 10;
            g0[j] = fmaf((float)m[hi0], (float)s[si0], g0[j]);
            g1[j] = fmaf((float)m[hi1], (float)s[si1], g1[j]);
            if (lane < 16) g2[j] = fmaf((float)m[hi2], (float)s[si2], g2[j]);
        }
    }
    for (int j = 0; i < end; ++i, ++j) {
        const _Float16* m = mixs + (size_t)i * 48;
        const _Float16* s = shs + (size_t)i * 10;
        g0[j] = fmaf((float)m[hi0], (float)s[si0], g0[j]);
        g1[j] = fmaf((float)m[hi1], (float)s[si1], g1[j]);
        if (lane < 16) g2[j] = fmaf((float)m[hi2], (float)s[si2], g2[j]);
    }
    float a0 = (g0[0] + g0[1]) + (g0[2] + g0[3]) + ((g0[4] + g0[5]) + (g0[6] + g0[7]));
    float a1 = (g1[0] + g1[1]) + (g1[2] + g1[3]) + ((g1[4] + g1[5]) + (g1[6] + g1[7]));
    float a2 = (g2[0] + g2[1]) + (g2[2] + g2[3]) + ((g2[4] + g2[5]) + (g2[6] + g2[7]));

    if (lane < 16) {   // self-interaction, 0e->0e only
        const float* xr = nf + (size_t)node * 16;
        float si = 0.0f;
        #pragma unroll
        for (int u = 0; u < 16; ++u)
            si = fmaf(xr[u], Wsi[u * 16 + lane], si);
        a0 = fmaf(si, 0.25f, a0);
    }

    float* orow = out + (size_t)node * 144;
    orow[lane] = a0;
    orow[lane + 64] = a1;
    if (lane < 16) orow[lane + 128] = a2;
}

// ------------------------- fallback (atomic path) --------------------------

__global__ __launch_bounds__(256)
void si_init_kernel(const float* __restrict__ nf, const float* __restrict__ Wsi,
                    float* __restrict__ out, int N) {
    int t = blockIdx.x * blockDim.x + threadIdx.x;
    int total = N * 144;
    if (t >= total) return;
    int n = t / 144;
    int c = t - n * 144;
    float val = 0.0f;
    if (c < 16) {
        const float* xr = nf + n * 16;
        #pragma unroll
        for (int u = 0; u < 16; ++u)
            val = fmaf(xr[u], Wsi[u * 16 + c], val);
        val *= 0.25f;
    }
    out[t] = val;
}

__global__ __launch_bounds__(256)
void edge_kernel_atomic(const float* __restrict__ nf, const int* __restrict__ ei,
                        const float* __restrict__ sh, const float* __restrict__ radial,
                        const float* __restrict__ W1, const float* __restrict__ W2,
                        float* __restrict__ out, int E) {
    int e = blockIdx.x * blockDim.x + threadIdx.x;
    if (e >= E) return;
    int src = ei[e];
    int dst = ei[E + e];
    float r[16], x[16];
    #pragma unroll
    for (int u = 0; u < 16; ++u) r[u] = radial[e * 16 + u] * 0.25f;
    #pragma unroll
    for (int u = 0; u < 16; ++u) x[u] = nf[src * 16 + u] * 0.03125f;
    float acc[48];
    #pragma unroll
    for (int j = 0; j < 48; ++j) acc[j] = 0.0f;
    for (int k = 0; k < 64; ++k) {
        float z = 0.0f;
        #pragma unroll
        for (int u = 0; u < 16; ++u) z = fmaf(r[u], W1[u * 64 + k], z);
        float hk = z / (1.0f + __expf(-z));
        const float* w2k = W2 + k * 768;
        #pragma unroll 4
        for (int u = 0; u < 16; ++u) {
            float p = hk * x[u];
            const float* w = w2k + u * 16;
            #pragma unroll
            for (int l = 0; l < 3; ++l)
                #pragma unroll
                for (int v = 0; v < 16; ++v)
                    acc[l * 16 + v] = fmaf(p, w[l * 256 + v], acc[l * 16 + v]);
        }
    }
    const float* she = sh + e * 9;
    float* orow = out + (long)dst * 144;
    #pragma unroll
    for (int v = 0; v < 16; ++v) atomicAdd(&orow[v], acc[v] * she[0]);
    #pragma unroll
    for (int v = 0; v < 16; ++v)
        for (int m = 0; m < 3; ++m)
            atomicAdd(&orow[16 + v * 3 + m], acc[16 + v] * she[1 + m]);
    #pragma unroll
    for (int v = 0; v < 16; ++v)
        for (int m = 0; m < 5; ++m)
            atomicAdd(&orow[64 + v * 5 + m], acc[32 + v] * she[4 + m]);
}

// ---------------------------------------------------------------------------

extern "C" void kernel_launch(void* const* d_in, const int* in_sizes, int n_in,
                              void* d_out, int out_size, void* d_ws, size_t ws_size,
                              hipStream_t stream) {
    const float* nf     = (const float*)d_in[0];
    const int*   ei     = (const int*)  d_in[1];
    const float* sh     = (const float*)d_in[2];
    const float* radial = (const float*)d_in[3];
    const float* W1     = (const float*)d_in[4];
    const float* W2     = (const float*)d_in[5];
    const float* Wsi    = (const float*)d_in[6];
    float* out = (float*)d_out;

    const int N = in_sizes[0] / 16;
    const int E = in_sizes[1] / 2;

    int n_scan = N + 1;
    int n_pad  = (n_scan + 32767) & ~32767;

    size_t mix_bytes  = (size_t)E * 48 * sizeof(_Float16);   // 96-B f16 rows
    size_t offs_bytes = (size_t)n_pad * sizeof(int);
    size_t curs_bytes = (size_t)N * sizeof(int);
    size_t shs_bytes  = (size_t)E * 10 * sizeof(_Float16);   // 20-B f16 sh rows
    size_t bfrag_off  = (mix_bytes + offs_bytes + curs_bytes + shs_bytes + 127) & ~(size_t)127;
    size_t bfrag_bytes = 96 * 512 * sizeof(_Float16);        // 96 KB
    size_t w1f_off    = bfrag_off + bfrag_bytes;
    size_t w1f_bytes  = 2048 * sizeof(_Float16);             // 4 KB
    size_t need = w1f_off + w1f_bytes;

    if (ws_size < need) {
        int total = N * 144;
        hipLaunchKernelGGL(si_init_kernel, dim3((total + 255) / 256), dim3(256), 0, stream,
                           nf, Wsi, out, N);
        hipLaunchKernelGGL(edge_kernel_atomic, dim3((E + 255) / 256), dim3(256), 0, stream,
                           nf, ei, sh, radial, W1, W2, out, E);
        return;
    }

    char* wsb = (char*)d_ws;
    _Float16* mixs = (_Float16*)wsb;
    int*   offs = (int*)(wsb + mix_bytes);
    int*   curs = (int*)(wsb + mix_bytes + offs_bytes);
    _Float16* shs = (_Float16*)(wsb + mix_bytes + offs_bytes + curs_bytes);
    _Float16* bfrag = (_Float16*)(wsb + bfrag_off);
    _Float16* w1frag = (_Float16*)(wsb + w1f_off);

    (void)hipMemsetAsync(offs, 0, offs_bytes + curs_bytes, stream);

    int eb = (E + 255) / 256;
    hipLaunchKernelGGL(prep_kernel, dim3(eb), dim3(256), 0, stream,
                       W2, W1, bfrag, w1frag, ei, offs, E);
    hipLaunchKernelGGL(scan_kernel, dim3(1), dim3(1024), 0, stream, offs, n_pad);
    hipLaunchKernelGGL(edge_mfma_kernel, dim3(eb), dim3(256), 0, stream,
                       nf, ei, radial, w1frag, sh, bfrag, offs, curs, mixs, shs, E);
    hipLaunchKernelGGL(gather_kernel, dim3((N + 3) / 4), dim3(256), 0, stream,
                       mixs, shs, offs, nf, Wsi, out, N);
}